// Round 2
// baseline (39506.714 us; speedup 1.0000x reference)
//
#include <hip/hip_runtime.h>
#include <math.h>
#include <stdint.h>

// ---- problem constants ----
static const int NS = 4096;    // samples
static const int MF = 1000;    // features
static const int NCOMP = 50;   // principal components

// out layout: pseudotime [4096] | transition [4096*4096] | pca [4096*50]
#define TR_OFF  ((size_t)4096)
#define PCA_OFF ((size_t)4096 + (size_t)4096*4096)
#define HH_GRID 250

// ---------------- column mean ----------------
__global__ void k_colsum(const float* __restrict__ x, float* __restrict__ part){
  int b = blockIdx.x, tid = threadIdx.x;
  float a0=0,a1=0,a2=0,a3=0;
  for (int r=b*64; r<b*64+64; r++){
    const float* row = x + (size_t)r*MF;
    if (tid      < MF) a0 += row[tid];
    if (tid+256  < MF) a1 += row[tid+256];
    if (tid+512  < MF) a2 += row[tid+512];
    if (tid+768  < MF) a3 += row[tid+768];
  }
  if (tid      < MF) part[b*MF+tid]     = a0;
  if (tid+256  < MF) part[b*MF+tid+256] = a1;
  if (tid+512  < MF) part[b*MF+tid+512] = a2;
  if (tid+768  < MF) part[b*MF+tid+768] = a3;
}

__global__ void k_colmean(const float* __restrict__ part, float* __restrict__ mean){
  int c = blockIdx.x*256 + threadIdx.x;
  if (c < MF){ float s=0; for (int b=0;b<64;b++) s += part[b*MF+c]; mean[c] = s/4096.0f; }
}

__global__ void k_barinit(unsigned* bar){ if (threadIdx.x < 2) bar[threadIdx.x] = 0u; }

// ---------------- cov = (x-mean)^T (x-mean) / (n-1), fp64 out ----------------
// Lower-triangle blocks only; mirror write (bitwise-identical values).
__global__ void k_cov(const float* __restrict__ x, const float* __restrict__ mean,
                      double* __restrict__ Ah){
  __shared__ float As[32][65];
  __shared__ float Bs[32][65];
  int bx = blockIdx.x, by = blockIdx.y;
  if (bx > by) return;
  int i0 = by*64, j0 = bx*64;
  int tx = threadIdx.x, ty = threadIdx.y;
  int tid = ty*16+tx;
  double acc[4][4];
  #pragma unroll
  for (int u=0;u<4;u++)
    #pragma unroll
    for (int v=0;v<4;v++) acc[u][v]=0.0;
  for (int k0=0;k0<4096;k0+=32){
    for (int t=tid;t<32*64;t+=256){
      int kk=t>>6, ii=t&63;
      int gi=i0+ii, gj=j0+ii;
      As[kk][ii] = (gi<MF) ? (x[(size_t)(k0+kk)*MF+gi]-mean[gi]) : 0.f;
      Bs[kk][ii] = (gj<MF) ? (x[(size_t)(k0+kk)*MF+gj]-mean[gj]) : 0.f;
    }
    __syncthreads();
    for (int kk=0;kk<32;kk++){
      float a[4], b[4];
      #pragma unroll
      for (int u=0;u<4;u++){ a[u]=As[kk][ty*4+u]; b[u]=Bs[kk][tx*4+u]; }
      #pragma unroll
      for (int u=0;u<4;u++)
        #pragma unroll
        for (int v=0;v<4;v++) acc[u][v] += (double)a[u]*(double)b[v];
    }
    __syncthreads();
  }
  #pragma unroll
  for (int u=0;u<4;u++)
    #pragma unroll
    for (int v=0;v<4;v++){
      int gi=i0+ty*4+u, gj=j0+tx*4+v;
      if (gi<MF && gj<MF){
        double val = acc[u][v]*(1.0/4095.0);
        Ah[(size_t)gi*MF+gj] = val;
        Ah[(size_t)gj*MF+gi] = val;
      }
    }
}

__device__ __forceinline__ unsigned wang(unsigned s){
  s=(s^61u)^(s>>16); s*=9u; s^=s>>4; s*=0x27d4eb2du; s^=s>>15; return s;
}

// ---- hand-rolled device-scope grid barrier (sense-reversing) ----
// Plain launch, grid=HH_GRID<=256 blocks, 1 block/CU guaranteed resident.
__device__ __forceinline__ void grid_sync(unsigned* bar){
  __syncthreads();
  if (threadIdx.x == 0){
    __threadfence();   // release: L2 writeback (agent scope) of this block's stores
    unsigned gen = __hip_atomic_load(&bar[1], __ATOMIC_RELAXED, __HIP_MEMORY_SCOPE_AGENT);
    unsigned prev = __hip_atomic_fetch_add(&bar[0], 1u, __ATOMIC_ACQ_REL, __HIP_MEMORY_SCOPE_AGENT);
    if (prev + 1u == (unsigned)HH_GRID){
      __hip_atomic_store(&bar[0], 0u, __ATOMIC_RELAXED, __HIP_MEMORY_SCOPE_AGENT);
      __hip_atomic_fetch_add(&bar[1], 1u, __ATOMIC_RELEASE, __HIP_MEMORY_SCOPE_AGENT);
    } else {
      while (__hip_atomic_load(&bar[1], __ATOMIC_RELAXED, __HIP_MEMORY_SCOPE_AGENT) == gen)
        __builtin_amdgcn_s_sleep(1);
    }
    __threadfence();   // acquire: invalidate stale L1/L2 before re-reading
  }
  __syncthreads();
}

// ======== persistent fp64 Householder tridiagonalization (all 998 steps) ====
// One launch; 1 grid sync per step. vprev persists in LDS (no Vh reload);
// tau of previous step kept in a register. Per-element arithmetic and all
// reduction orders are bitwise-identical to the previously-verified version.
__global__ void __launch_bounds__(256) k_hh_all(double* Ah,
                                                double* __restrict__ Vh,
                                                double* __restrict__ tauv,
                                                double* __restrict__ betaH,
                                                double* w1a, double* w1b,
                                                double* cola, double* colb,
                                                unsigned* bar){
  __shared__ double vbuf[2][1000];
  __shared__ double wfull[1000];
  __shared__ double red4[4], redb[4];
  __shared__ double sAlpha;
  int tid = threadIdx.x;
  int lane = tid & 63, wv = tid >> 6;
  double tau_prev = 0.0;

  for (int k = 0; k < 998; k++){
    double* vk    = vbuf[k & 1];
    double* vprev = vbuf[(k & 1) ^ 1];
    const double* w1prev  = (k & 1) ? w1a : w1b;
    double*       w1next  = (k & 1) ? w1b : w1a;
    const double* colprev = (k & 1) ? cola : colb;
    double*       colnext = (k & 1) ? colb : cola;

    // ---- prologue: vdot = v_{k-1}^T w1_{k-1}; wfull = tau*w1 - hts*v ----
    double vd = 0.0;
    if (k > 0){
      for (int j = k + tid; j < 1000; j += 256){
        double ww = w1prev[j];
        wfull[j] = ww;
        vd += vprev[j]*ww;
      }
    }
    #pragma unroll
    for (int off=32; off; off>>=1) vd += __shfl_down(vd, off, 64);
    if (lane==0) red4[wv] = vd;
    __syncthreads();                                   // B1
    double vdot = red4[0]+red4[1]+red4[2]+red4[3];
    double tp  = tau_prev;
    double hts = 0.5*tp*tp*vdot;
    if (k > 0){
      for (int j = k + tid; j < 1000; j += 256)
        wfull[j] = tp*wfull[j] - hts*vprev[j];
    }
    __syncthreads();                                   // B2: wfull ready

    // ---- updated column k -> vk[], alpha & tail norm ----
    double a2 = 0.0;
    for (int j = k+1 + tid; j < 1000; j += 256){
      double c;
      if (k > 0) c = colprev[j] - (vprev[j]*wfull[k] + wfull[j]*vprev[k]);
      else       c = Ah[(size_t)j*MF + k];
      vk[j] = c;
      if (j == k+1) sAlpha = c;          // tid 0; race-free alpha staging
      if (j > k+1) a2 += c*c;
    }
    #pragma unroll
    for (int off=32; off; off>>=1) a2 += __shfl_down(a2, off, 64);
    if (lane==0) redb[wv] = a2;
    __syncthreads();                                   // B3
    double xn2 = redb[0]+redb[1]+redb[2]+redb[3];
    double alpha = sAlpha;
    double beta, tau, scl;
    if (xn2 == 0.0){ beta = alpha; tau = 0.0; scl = 0.0; }
    else {
      double nrm = sqrt(alpha*alpha + xn2);
      beta = (alpha >= 0.0) ? -nrm : nrm;              // dlarfg sign
      tau  = (beta - alpha)/beta;
      scl  = 1.0/(alpha - beta);
    }
    if (tid==0 && blockIdx.x==0){
      tauv[k]=tau; betaH[k]=beta;
      if (k>0) Ah[(size_t)k*MF + k] -= 2.0*wfull[k];   // row-k diagonal fix
    }
    for (int j = k+1 + tid; j < 1000; j += 256)
      vk[j] = (j == k+1) ? 1.0 : vk[j]*scl;
    __syncthreads();                                   // B4: vk ready
    if (blockIdx.x==0){
      for (int j = k+1 + tid; j < 1000; j += 256)
        Vh[(size_t)k*MF + j] = vk[j];
    }

    // ---- wave-per-row pass: apply update k-1, fused symv, stage col k+1 ----
    for (int r = k+1 + blockIdx.x*4 + wv; r < 1000; r += HH_GRID*4){
      double vr = (k>0)? vprev[r] : 0.0;
      double wr = (k>0)? wfull[r] : 0.0;
      double* row = Ah + (size_t)r*MF;
      double acc = 0.0;
      for (int c = k+1 + lane; c < 1000; c += 64){
        double a = row[c];
        if (k > 0){ a -= vr*wfull[c] + wr*vprev[c]; row[c] = a; }
        acc += a*vk[c];
        if (c == k+1) colnext[r] = a;
      }
      #pragma unroll
      for (int off=32; off; off>>=1) acc += __shfl_down(acc, off, 64);
      if (lane==0) w1next[r] = acc;
    }

    grid_sync(bar);
    tau_prev = tau;
  }
}

__device__ __forceinline__ int sgnchg(double a, double b){
  return (int)(((unsigned long long)(__double_as_longlong(a) ^ __double_as_longlong(b))) >> 63);
}

// ---- fin (trailing 2x2) + extract (diag/subdiag) + Sturm bisection, fused ----
__global__ void k_post(double* __restrict__ Ah, const double* __restrict__ Vh,
                       const double* __restrict__ tauv, const double* __restrict__ w1last,
                       double* __restrict__ alphaH, double* __restrict__ betaH,
                       double* __restrict__ lamT){
  __shared__ double al[1000], abv[1000], bb[1000];
  int tid = threadIdx.x;
  if (tid==0){
    double v8 = Vh[(size_t)997*MF + 998];   // == 1.0
    double v9 = Vh[(size_t)997*MF + 999];
    double w18 = w1last[998], w19 = w1last[999];
    double tau = tauv[997];
    double vdot = v8*w18 + v9*w19;
    double hts = 0.5*tau*tau*vdot;
    double w8 = tau*w18 - hts*v8;
    double w9 = tau*w19 - hts*v9;
    Ah[(size_t)998*MF+998] -= v8*w8 + w8*v8;
    Ah[(size_t)999*MF+998] -= v9*w8 + w9*v8;
    Ah[(size_t)999*MF+999] -= v9*w9 + w9*v9;
  }
  __syncthreads();
  for (int t=tid;t<1000;t+=64){
    double a2 = Ah[(size_t)t*MF+t];
    alphaH[t]=a2; al[t]=a2;
  }
  if (tid==0) betaH[998] = Ah[(size_t)999*MF+998];
  __syncthreads();
  for (int t=tid;t<1000;t+=64){
    double b = (t<999)? betaH[t] : 0.0;
    abv[t]=fabs(b); bb[t]=b*b;
  }
  __syncthreads();
  if (tid >= NCOMP) return;
  int i = tid;
  double lo=1e300, hi=-1e300;
  for (int k2=0;k2<1000;k2++){
    double bl = (k2>0)? abv[k2-1] : 0.0;
    double br = (k2<999)? abv[k2] : 0.0;
    double a = al[k2];
    lo = fmin(lo, a-bl-br);
    hi = fmax(hi, a+bl+br);
  }
  int target = 999 - i;
  for (int it=0; it<55; it++){
    double mid = 0.5*(lo+hi);
    int cnt = 0;
    double d1 = 1.0;
    double d0 = al[0]-mid;
    cnt += (int)(((unsigned long long)__double_as_longlong(d0))>>63);
    int k2 = 1;
    for (; k2+3 < 1000; k2 += 4){
      double n0 = (al[k2  ]-mid)*d0 - bb[k2-1]*d1;
      double n1 = (al[k2+1]-mid)*n0 - bb[k2  ]*d0;
      double n2 = (al[k2+2]-mid)*n1 - bb[k2+1]*n0;
      double n3 = (al[k2+3]-mid)*n2 - bb[k2+2]*n1;
      cnt += sgnchg(n0,d0)+sgnchg(n1,n0)+sgnchg(n2,n1)+sgnchg(n3,n2);
      double mm = fmax(fabs(n3), fabs(n2));
      double s = (mm > 1e250) ? 1e-250 : ((mm < 1e-250) ? 1e250 : 1.0);
      d1 = n2*s; d0 = n3*s;
    }
    for (; k2 < 1000; k2++){
      double nn = (al[k2]-mid)*d0 - bb[k2-1]*d1;
      cnt += sgnchg(nn, d0);
      d1 = d0; d0 = nn;
    }
    if (cnt > target) hi = mid; else lo = mid;
  }
  lamT[i] = 0.5*(lo+hi);
}

// ---- serial pivoted tridiagonal solve (LAPACK dgtsv replica), thread-0 only ----
__device__ void gtsv_serial(int m, double* dl, double* dd, double* du, double* x){
  for (int r=0;r<m-1;r++){
    if (fabs(dd[r]) >= fabs(dl[r])){
      if (dd[r] != 0.0){
        double fact = dl[r]/dd[r];
        dd[r+1] -= fact*du[r];
        x[r+1]  -= fact*x[r];
      }
      if (r < m-2) dl[r] = 0.0;
    } else {
      double fact = dd[r]/dl[r];
      dd[r] = dl[r];
      double tdd = dd[r+1];
      dd[r+1] = du[r] - fact*tdd;
      if (r < m-2){
        double tdu = du[r+1];
        dl[r] = tdu;
        du[r+1] = -fact*tdu;
      }
      du[r] = tdd;
      double t2 = x[r]; x[r] = x[r+1]; x[r+1] = t2 - fact*x[r+1];
    }
  }
  x[m-1] /= dd[m-1];
  if (m >= 2) x[m-2] = (x[m-2] - du[m-2]*x[m-1])/dd[m-2];
  for (int r=m-3;r>=0;r--)
    x[r] = (x[r] - du[r]*x[r+1] - dl[r]*x[r+2])/dd[r];
}

// ---- inverse iteration + D&C sign replication, fused (one block per eigpair) ----
__global__ void __launch_bounds__(256) k_invsign(const double* __restrict__ alphaH,
                                                 const double* __restrict__ betaH,
                                                 const double* __restrict__ lamT,
                                                 double* __restrict__ V50,
                                                 float* __restrict__ sgnv){
  __shared__ double v[1000], xx[1000], dd[1000], du[1000], dl[1000];
  __shared__ double red[256];
  __shared__ double lam_s;
  __shared__ int ab[2];
  __shared__ float sig;
  int i = blockIdx.x, tid = threadIdx.x;
  double lam = lamT[i];
  for (int t=tid;t<1000;t+=256){
    unsigned h = wang((unsigned)(i*1000+t)*2654435761u + 777u);
    v[t] = (double)(h & 0xffffffu)/8388608.0 - 1.0;
  }
  __syncthreads();
  for (int it=0; it<3; it++){
    for (int t=tid;t<1000;t+=256){
      dd[t] = alphaH[t]-lam;
      if (t<999){ du[t]=betaH[t]; dl[t]=betaH[t]; }
      xx[t] = v[t];
    }
    __syncthreads();
    if (tid==0) gtsv_serial(1000, dl, dd, du, xx);
    __syncthreads();
    double a=0; for (int t=tid;t<1000;t+=256) a += xx[t]*xx[t];
    red[tid]=a; __syncthreads();
    for (int off=128;off;off>>=1){ if(tid<off) red[tid]+=red[tid+off]; __syncthreads(); }
    double inv = 1.0/sqrt(red[0]);
    __syncthreads();
    for (int t=tid;t<1000;t+=256) v[t]=xx[t]*inv;
    __syncthreads();
  }
  // Rayleigh quotient -> refined lambda (kept in LDS; no global round trip)
  double a=0;
  for (int t=tid;t<1000;t+=256){
    double s = alphaH[t]*v[t];
    if (t>0)   s += betaH[t-1]*v[t-1];
    if (t<999) s += betaH[t]*v[t+1];
    a += v[t]*s;
  }
  red[tid]=a; __syncthreads();
  for (int off=128;off;off>>=1){ if(tid<off) red[tid]+=red[tid+off]; __syncthreads(); }
  if (tid==0){ lam_s = red[0]; ab[0]=0; ab[1]=1000; sig=1.f; }
  for (int t=tid;t<1000;t+=256) V50[(size_t)i*1000+t]=v[t];
  __syncthreads();
  // ---- sign phase (operates on v in place; V50 already stored) ----
  while (true){
    int a0=ab[0], b0=ab[1];
    if (b0-a0 <= 25) break;
    int c = a0 + (b0-a0)/2;
    double m1=0,m2=0;
    for (int t=a0+tid;t<b0;t+=256){ double q=v[t]*v[t]; if (t<c) m1+=q; else m2+=q; }
    red[tid]=m1; __syncthreads();
    for (int off=128;off;off>>=1){ if(tid<off) red[tid]+=red[tid+off]; __syncthreads(); }
    double M1=red[0]; __syncthreads();
    red[tid]=m2; __syncthreads();
    for (int off=128;off;off>>=1){ if(tid<off) red[tid]+=red[tid+off]; __syncthreads(); }
    double M2=red[0]; __syncthreads();
    double tot=M1+M2;
    if (fmin(M1,M2) <= 1e-10*tot){
      if (tid==0){ if (M1>=M2) ab[1]=c; else ab[0]=c; }
      __syncthreads();
      a0=ab[0]; b0=ab[1];
      double nn=0; for (int t=a0+tid;t<b0;t+=256) nn+=v[t]*v[t];
      red[tid]=nn; __syncthreads();
      for (int off=128;off;off>>=1){ if(tid<off) red[tid]+=red[tid+off]; __syncthreads(); }
      double inv = 1.0/sqrt(red[0]); __syncthreads();
      for (int t=a0+tid;t<b0;t+=256) v[t]*=inv;
      __syncthreads();
      for (int it=0; it<2; it++){
        for (int t=a0+tid;t<b0;t+=256){
          int L=t-a0;
          dd[L]=alphaH[t]-lam_s;
          if (t<b0-1){ du[L]=betaH[t]; dl[L]=betaH[t]; }
          xx[L]=v[t];
        }
        __syncthreads();
        if (tid==0) gtsv_serial(b0-a0, dl, dd, du, xx);
        __syncthreads();
        double s2=0; for (int t=a0+tid;t<b0;t+=256){ double q=xx[t-a0]; s2+=q*q; }
        red[tid]=s2; __syncthreads();
        for (int off=128;off;off>>=1){ if(tid<off) red[tid]+=red[tid+off]; __syncthreads(); }
        double inv2 = 1.0/sqrt(red[0]); __syncthreads();
        for (int t=a0+tid;t<b0;t+=256) v[t]=xx[t-a0]*inv2;
        __syncthreads();
      }
      double rq=0;
      for (int t=a0+tid;t<b0;t+=256){
        double s = alphaH[t]*v[t];
        if (t>a0)   s += betaH[t-1]*v[t-1];
        if (t<b0-1) s += betaH[t]*v[t+1];
        rq += v[t]*s;
      }
      red[tid]=rq; __syncthreads();
      for (int off=128;off;off>>=1){ if(tid<off) red[tid]+=red[tid+off]; __syncthreads(); }
      if (tid==0) lam_s=red[0];
      __syncthreads();
      continue;
    }
    if (tid==0){
      double vc1 = v[c-1], vc = v[c];
      if (fabs(vc1) >= fabs(vc)){
        sig = (vc1 < 0.0) ? 1.f : -1.f;
      } else {
        double req = (betaH[c-1] >= 0.0) ? -1.0 : 1.0;
        double have = (vc >= 0.0) ? 1.0 : -1.0;
        sig = (have == req) ? 1.f : -1.f;
      }
    }
    break;
  }
  __syncthreads();
  if (tid==0) sgnv[i]=sig;
}

// ---- m_i = Q v_i (descending reflectors): u in registers, 1 barrier/reflector ----
__global__ void __launch_bounds__(256) k_applyQm(const double* __restrict__ Vh,
                                                 const double* __restrict__ tauv,
                                                 const double* __restrict__ V50,
                                                 const float* __restrict__ sgnv,
                                                 float* __restrict__ E50){
  __shared__ double red2[2][4];
  __shared__ double tl[1000];
  int i = blockIdx.x, tid = threadIdx.x;
  int lane = tid & 63, wv = tid >> 6;
  int base = tid*4;                        // thread owns u[base..base+3]
  for (int t=tid;t<1000;t+=256) tl[t] = tauv[t];
  const double* src = V50 + (size_t)i*1000;
  double u0=0,u1=0,u2=0,u3=0;
  if (base < 1000){
    u0 = src[base]; u1 = src[base+1]; u2 = src[base+2]; u3 = src[base+3];
  }
  __syncthreads();
  for (int k=997;k>=0;k--){
    const double* v = Vh + (size_t)k*MF;
    double a = 0.0, v0=0,v1=0,v2=0,v3=0;
    if (base < 1000 && base+3 >= k+1){
      if (base   >= k+1){ v0 = v[base  ]; a += v0*u0; }
      if (base+1 >= k+1){ v1 = v[base+1]; a += v1*u1; }
      if (base+2 >= k+1){ v2 = v[base+2]; a += v2*u2; }
      if (base+3 >= k+1){ v3 = v[base+3]; a += v3*u3; }
    }
    #pragma unroll
    for (int off=32; off; off>>=1) a += __shfl_down(a, off, 64);
    if (lane==0) red2[k&1][wv] = a;
    __syncthreads();
    double td = tl[k]*(red2[k&1][0]+red2[k&1][1]+red2[k&1][2]+red2[k&1][3]);
    u0 -= td*v0; u1 -= td*v1; u2 -= td*v2; u3 -= td*v3;
  }
  double s = (double)sgnv[i];
  if (base < 1000){
    E50[(size_t)(base  )*NCOMP + i] = (float)(u0*s);
    E50[(size_t)(base+1)*NCOMP + i] = (float)(u1*s);
    E50[(size_t)(base+2)*NCOMP + i] = (float)(u2*s);
    E50[(size_t)(base+3)*NCOMP + i] = (float)(u3*s);
  }
}

// ---------------- P = (x-mean) * E -> d_out pca region ----------------
__global__ void k_pca(const float* __restrict__ x, const float* __restrict__ mean,
                      const float* __restrict__ E, float* __restrict__ P){
  __shared__ float As[64][65];
  __shared__ float Es[64][65];
  int r0 = blockIdx.x*64;
  int tx = threadIdx.x & 15, ty = threadIdx.x >> 4;
  float acc[4][4];
  #pragma unroll
  for (int u=0;u<4;u++)
    #pragma unroll
    for (int v=0;v<4;v++) acc[u][v]=0.f;
  for (int k0=0;k0<MF;k0+=64){
    for (int t=threadIdx.x;t<64*64;t+=256){
      int i=t>>6, kk=t&63; int k=k0+kk;
      As[i][kk] = (k<MF) ? (x[(size_t)(r0+i)*MF+k]-mean[k]) : 0.f;
    }
    for (int t=threadIdx.x;t<64*65;t+=256){
      int kk=t/65, c=t%65; int k=k0+kk;
      Es[kk][c] = (k<MF && c<NCOMP) ? E[(size_t)k*NCOMP+c] : 0.f;
    }
    __syncthreads();
    for (int kk=0;kk<64;kk++){
      float a[4], b[4];
      #pragma unroll
      for (int u=0;u<4;u++){ a[u]=As[ty*4+u][kk]; b[u]=Es[kk][tx*4+u]; }
      #pragma unroll
      for (int u=0;u<4;u++)
        #pragma unroll
        for (int v=0;v<4;v++) acc[u][v] += a[u]*b[v];
    }
    __syncthreads();
  }
  #pragma unroll
  for (int u=0;u<4;u++){
    int r=r0+ty*4+u;
    #pragma unroll
    for (int v=0;v<4;v++){
      int c=tx*4+v;
      if (c<NCOMP) P[(size_t)r*NCOMP+c] = acc[u][v];
    }
  }
}

// ---------------- row squared norms ----------------
__global__ void k_rowsq(const float* __restrict__ P, float* __restrict__ sqv){
  int r = blockIdx.x*256 + threadIdx.x;
  if (r < NS){
    float s=0;
    for (int c=0;c<NCOMP;c++){ float v=P[(size_t)r*NCOMP+c]; s+=v*v; }
    sqv[r]=s;
  }
}

// ---------------- fused d2 + top-15 + transition row + diff weights ----------------
__global__ void k_knn(const float* __restrict__ P, const float* __restrict__ sqv,
                      float* __restrict__ trans, int* __restrict__ kidx,
                      float* __restrict__ kwd){
  __shared__ float pi[64];
  __shared__ unsigned long long keys[16*256];
  __shared__ unsigned long long redk[4];
  __shared__ unsigned long long wink[15];
  __shared__ float wt[15], wd[15], sums[2];
  int i = blockIdx.x, tid = threadIdx.x;
  int lane = tid & 63, wv = tid >> 6;
  for (int t=tid;t<NCOMP;t+=256) pi[t] = P[(size_t)i*NCOMP+t];
  __syncthreads();
  float sqi = sqv[i];
  for (int s2=0;s2<16;s2++){
    int j = tid + s2*256;
    float dot=0;
    for (int c=0;c<NCOMP;c++) dot += pi[c]*P[(size_t)j*NCOMP+c];
    float d2 = sqi + sqv[j] - 2.f*dot;
    d2 = fmaxf(d2, 0.f);
    unsigned int db = __float_as_uint(d2);
    keys[s2*256+tid] = ((unsigned long long)db<<32) | (unsigned)j;
  }
  __syncthreads();
  for (int rsel=0;rsel<15;rsel++){
    unsigned long long m = ~0ull;
    #pragma unroll
    for (int s2=0;s2<16;s2++){
      unsigned long long k = keys[s2*256+tid];
      m = (k<m)?k:m;
    }
    #pragma unroll
    for (int off=32; off; off>>=1){
      unsigned long long o = __shfl_down(m, off, 64);
      m = (o<m)?o:m;
    }
    if (lane==0) redk[wv]=m;
    __syncthreads();
    unsigned long long w = redk[0];
    if (redk[1]<w) w=redk[1];
    if (redk[2]<w) w=redk[2];
    if (redk[3]<w) w=redk[3];
    if (tid==0) wink[rsel]=w;
    #pragma unroll
    for (int s2=0;s2<16;s2++)
      if (keys[s2*256+tid]==w) keys[s2*256+tid]=~0ull;
    __syncthreads();
  }
  if (tid<15){
    unsigned long long w = wink[tid];
    float d2 = __uint_as_float((unsigned)(w>>32));
    wt[tid] = expf(-0.5f*d2);
    wd[tid] = expf(-d2);
  }
  __syncthreads();
  if (tid==0){
    float st=0, sd=0;
    for (int k=0;k<15;k++){ st+=wt[k]; sd+=wd[k]; }
    sums[0]=st; sums[1]=sd;
  }
  __syncthreads();
  float* row = trans + (size_t)i*NS;
  for (int c=tid;c<NS;c+=256) row[c]=0.f;
  __syncthreads();
  if (tid<15){
    int j = (int)(wink[tid] & 0xffffffffull);
    row[j] = wt[tid]/sums[0];
    kidx[i*15+tid] = j;
    kwd[i*15+tid]  = wd[tid]/sums[1];
  }
}

// ---------------- 100-iteration sparse power iteration ----------------
__global__ void __launch_bounds__(1024) k_power(const int* __restrict__ kidx,
                                                const float* __restrict__ kwd,
                                                float* __restrict__ outPT){
  __shared__ float d[4096];
  __shared__ float dn[4096];
  __shared__ float red[16];
  int tid = threadIdx.x;
  int lane = tid & 63, wv = tid >> 6;
  for (int t=tid;t<4096;t+=1024) d[t] = (t==0)?1.f:0.f;
  __syncthreads();
  for (int it=0; it<100; it++){
    float lmax = 0.f;
    for (int r=tid;r<4096;r+=1024){
      float a=0;
      #pragma unroll
      for (int k=0;k<15;k++) a += kwd[r*15+k]*d[kidx[r*15+k]];
      dn[r]=a;
      lmax = fmaxf(lmax, a);
    }
    #pragma unroll
    for (int off=32; off; off>>=1) lmax = fmaxf(lmax, __shfl_down(lmax, off, 64));
    if (lane==0) red[wv]=lmax;
    __syncthreads();
    float m = red[0];
    #pragma unroll
    for (int w=1;w<16;w++) m = fmaxf(m, red[w]);
    for (int r=tid;r<4096;r+=1024) d[r]=dn[r]/m;
    __syncthreads();
  }
  for (int t=tid;t<4096;t+=1024) outPT[t]=d[t];
}

// ---------------- host ----------------
// Footprint ~16.93 MB. Ah dies after k_post; sqv/kidx/kwd overlay it.
extern "C" void kernel_launch(void* const* d_in, const int* in_sizes, int n_in,
                              void* d_out, int out_size, void* d_ws, size_t ws_size,
                              hipStream_t stream){
  const float* x = (const float*)d_in[0];
  float* out = (float*)d_out;
  char* base = (char*)d_ws;

  double* Ah     = (double*)(base + 0);            // 8,000,000 (dead after k_post)
  float*  sqv    = (float*) (base + 0);            //    16,384 overlay
  int*    kidx   = (int*)   (base + 16384);        //   245,760 overlay
  float*  kwd    = (float*) (base + 262144);       //   245,760 overlay (ends 507,904)
  double* Vh     = (double*)(base + 8000000);      // 8,000,000
  double* V50    = (double*)(base + 16000000);     //   400,000
  float*  E50    = (float*) (base + 16400000);     //   200,000
  float*  part   = (float*) (base + 16600000);     //   256,000
  float*  mean   = (float*) (base + 16856000);     //     4,000
  double* tauv   = (double*)(base + 16860000);     //     8,000
  double* betaH  = (double*)(base + 16868000);     //     8,000
  double* alphaH = (double*)(base + 16876000);     //     8,000
  double* w1a    = (double*)(base + 16884000);     //     8,000
  double* w1b    = (double*)(base + 16892000);     //     8,000
  double* cola   = (double*)(base + 16900000);     //     8,000
  double* colb   = (double*)(base + 16908000);     //     8,000
  double* lamT   = (double*)(base + 16916000);     //       400
  float*  sgnv   = (float*) (base + 16916400);     //       200
  unsigned* bar  = (unsigned*)(base + 16917000);   //         8

  k_colsum<<<64,256,0,stream>>>(x, part);
  k_colmean<<<4,256,0,stream>>>(part, mean);
  k_barinit<<<1,64,0,stream>>>(bar);
  k_cov<<<dim3(16,16),dim3(16,16),0,stream>>>(x, mean, Ah);

  // persistent fp64 Householder tridiagonalization (single launch, 998 steps)
  k_hh_all<<<HH_GRID,256,0,stream>>>(Ah, Vh, tauv, betaH, w1a, w1b, cola, colb, bar);

  // fin + extract + top-50 Sturm bisection
  k_post<<<1,64,0,stream>>>(Ah, Vh, tauv, w1b, alphaH, betaH, lamT);

  // inverse iteration + D&C sign replication (fused)
  k_invsign<<<50,256,0,stream>>>(alphaH, betaH, lamT, V50, sgnv);

  // back-transform + sign -> eigenvectors, then outputs
  k_applyQm<<<50,256,0,stream>>>(Vh, tauv, V50, sgnv, E50);
  k_pca<<<64,256,0,stream>>>(x, mean, E50, out + PCA_OFF);
  k_rowsq<<<16,256,0,stream>>>(out + PCA_OFF, sqv);
  k_knn<<<4096,256,0,stream>>>(out + PCA_OFF, sqv, out + TR_OFF, kidx, kwd);
  k_power<<<1,1024,0,stream>>>(kidx, kwd, out);
}

// Round 3
// 17339.362 us; speedup vs baseline: 2.2784x; 2.2784x over previous
//
#include <hip/hip_runtime.h>
#include <math.h>
#include <stdint.h>

// ---- problem constants ----
static const int NS = 4096;    // samples
static const int MF = 1000;    // features
static const int NCOMP = 50;   // principal components
#define AH_LD 1024             // padded Ah leading dim: rows = 64 full cachelines,
                               // no line shared between two owner blocks

// out layout: pseudotime [4096] | transition [4096*4096] | pca [4096*50]
#define TR_OFF  ((size_t)4096)
#define PCA_OFF ((size_t)4096 + (size_t)4096*4096)
#define HH_GRID 250

// ---------------- column mean ----------------
__global__ void k_colsum(const float* __restrict__ x, float* __restrict__ part){
  int b = blockIdx.x, tid = threadIdx.x;
  float a0=0,a1=0,a2=0,a3=0;
  for (int r=b*64; r<b*64+64; r++){
    const float* row = x + (size_t)r*MF;
    if (tid      < MF) a0 += row[tid];
    if (tid+256  < MF) a1 += row[tid+256];
    if (tid+512  < MF) a2 += row[tid+512];
    if (tid+768  < MF) a3 += row[tid+768];
  }
  if (tid      < MF) part[b*MF+tid]     = a0;
  if (tid+256  < MF) part[b*MF+tid+256] = a1;
  if (tid+512  < MF) part[b*MF+tid+512] = a2;
  if (tid+768  < MF) part[b*MF+tid+768] = a3;
}

__global__ void k_colmean(const float* __restrict__ part, float* __restrict__ mean){
  int c = blockIdx.x*256 + threadIdx.x;
  if (c < MF){ float s=0; for (int b=0;b<64;b++) s += part[b*MF+c]; mean[c] = s/4096.0f; }
}

__global__ void k_barinit(unsigned long long* bar){ if (threadIdx.x==0) *bar = 0ull; }

// ---------------- cov = (x-mean)^T (x-mean) / (n-1), fp64 out ----------------
// Lower-triangle blocks only; mirror write (bitwise-identical values).
__global__ void k_cov(const float* __restrict__ x, const float* __restrict__ mean,
                      double* __restrict__ Ah){
  __shared__ float As[32][65];
  __shared__ float Bs[32][65];
  int bx = blockIdx.x, by = blockIdx.y;
  if (bx > by) return;
  int i0 = by*64, j0 = bx*64;
  int tx = threadIdx.x, ty = threadIdx.y;
  int tid = ty*16+tx;
  double acc[4][4];
  #pragma unroll
  for (int u=0;u<4;u++)
    #pragma unroll
    for (int v=0;v<4;v++) acc[u][v]=0.0;
  for (int k0=0;k0<4096;k0+=32){
    for (int t=tid;t<32*64;t+=256){
      int kk=t>>6, ii=t&63;
      int gi=i0+ii, gj=j0+ii;
      As[kk][ii] = (gi<MF) ? (x[(size_t)(k0+kk)*MF+gi]-mean[gi]) : 0.f;
      Bs[kk][ii] = (gj<MF) ? (x[(size_t)(k0+kk)*MF+gj]-mean[gj]) : 0.f;
    }
    __syncthreads();
    for (int kk=0;kk<32;kk++){
      float a[4], b[4];
      #pragma unroll
      for (int u=0;u<4;u++){ a[u]=As[kk][ty*4+u]; b[u]=Bs[kk][tx*4+u]; }
      #pragma unroll
      for (int u=0;u<4;u++)
        #pragma unroll
        for (int v=0;v<4;v++) acc[u][v] += (double)a[u]*(double)b[v];
    }
    __syncthreads();
  }
  #pragma unroll
  for (int u=0;u<4;u++)
    #pragma unroll
    for (int v=0;v<4;v++){
      int gi=i0+ty*4+u, gj=j0+tx*4+v;
      if (gi<MF && gj<MF){
        double val = acc[u][v]*(1.0/4095.0);
        Ah[(size_t)gi*AH_LD+gj] = val;
        Ah[(size_t)gj*AH_LD+gi] = val;
      }
    }
}

__device__ __forceinline__ unsigned wang(unsigned s){
  s=(s^61u)^(s>>16); s*=9u; s^=s>>4; s*=0x27d4eb2du; s^=s>>15; return s;
}

// ---- device-coherent (agent-scope, relaxed) 8B load/store: write-through to
// the coherence point, NO L2 writeback/invalidate fences ----
__device__ __forceinline__ double cohLoadD(const double* p){
  unsigned long long v = __hip_atomic_load((const unsigned long long*)p,
      __ATOMIC_RELAXED, __HIP_MEMORY_SCOPE_AGENT);
  return __longlong_as_double((long long)v);
}
__device__ __forceinline__ void cohStoreD(double* p, double v){
  __hip_atomic_store((unsigned long long*)p,
      (unsigned long long)__double_as_longlong(v),
      __ATOMIC_RELAXED, __HIP_MEMORY_SCOPE_AGENT);
}

// ---- fence-free grid barrier: packed {gen:32, count:32}, one relaxed atomic.
// Last arrival adds (1<<32)-GRID: bumps gen AND resets count atomically.
__device__ __forceinline__ void grid_sync_fast(unsigned long long* bar){
  __syncthreads();
  if (threadIdx.x == 0){
    asm volatile("s_waitcnt vmcnt(0)" ::: "memory");  // drain coherent stores
    unsigned long long old = __hip_atomic_fetch_add(bar, 1ull,
        __ATOMIC_RELAXED, __HIP_MEMORY_SCOPE_AGENT);
    if ((unsigned)(old & 0xffffffffull) == (unsigned)(HH_GRID-1)){
      __hip_atomic_fetch_add(bar, (1ull<<32) - (unsigned long long)HH_GRID,
          __ATOMIC_RELAXED, __HIP_MEMORY_SCOPE_AGENT);
    } else {
      unsigned gen = (unsigned)(old >> 32);
      while ((unsigned)(__hip_atomic_load(bar, __ATOMIC_RELAXED,
                 __HIP_MEMORY_SCOPE_AGENT) >> 32) == gen)
        __builtin_amdgcn_s_sleep(1);
    }
  }
  __syncthreads();
}

// ======== persistent fp64 Householder tridiagonalization (all 998 steps) ====
// Fixed row ownership: wave wv of block b owns row r = b + 250*wv forever ->
// Ah rows stay dirty in the owner's XCD L2, never cross XCDs. Only w1/col
// (8KB each) cross blocks, via agent-scope write-through. Zero fences.
// Arithmetic + reduction orders bitwise-identical to the verified version.
__global__ void __launch_bounds__(256) k_hh_all(double* Ah,
                                                double* __restrict__ Vh,
                                                double* __restrict__ tauv,
                                                double* __restrict__ betaH,
                                                double* w1a, double* w1b,
                                                double* cola, double* colb,
                                                unsigned long long* bar){
  __shared__ double vbuf[2][1000];
  __shared__ double wfull[1000];
  __shared__ double red4[4], redb[4];
  __shared__ double sAlpha;
  int tid = threadIdx.x;
  int lane = tid & 63, wv = tid >> 6;
  int bid = blockIdx.x;
  int myrow = bid + wv*HH_GRID;           // fixed ownership (wave-level)
  double tau_prev = 0.0;

  for (int k = 0; k < 998; k++){
    double* vk    = vbuf[k & 1];
    double* vprev = vbuf[(k & 1) ^ 1];
    const double* w1prev  = (k & 1) ? w1a : w1b;
    double*       w1next  = (k & 1) ? w1b : w1a;
    const double* colprev = (k & 1) ? cola : colb;
    double*       colnext = (k & 1) ? colb : cola;

    // ---- prologue: vdot = v_{k-1}^T w1_{k-1}; wfull = tau*w1 - hts*v ----
    double vd = 0.0;
    if (k > 0){
      for (int j = k + tid; j < 1000; j += 256){
        double ww = cohLoadD(&w1prev[j]);
        wfull[j] = ww;
        vd += vprev[j]*ww;
      }
    }
    #pragma unroll
    for (int off=32; off; off>>=1) vd += __shfl_down(vd, off, 64);
    if (lane==0) red4[wv] = vd;
    __syncthreads();                                   // B1
    double vdot = red4[0]+red4[1]+red4[2]+red4[3];
    double tp  = tau_prev;
    double hts = 0.5*tp*tp*vdot;
    if (k > 0){
      for (int j = k + tid; j < 1000; j += 256)
        wfull[j] = tp*wfull[j] - hts*vprev[j];
    }
    __syncthreads();                                   // B2: wfull ready

    // ---- updated column k -> vk[], alpha & tail norm ----
    double a2 = 0.0;
    for (int j = k+1 + tid; j < 1000; j += 256){
      double c;
      if (k > 0) c = cohLoadD(&colprev[j]) - (vprev[j]*wfull[k] + wfull[j]*vprev[k]);
      else       c = Ah[(size_t)j*AH_LD + k];
      vk[j] = c;
      if (j == k+1) sAlpha = c;          // tid 0; race-free alpha staging
      if (j > k+1) a2 += c*c;
    }
    #pragma unroll
    for (int off=32; off; off>>=1) a2 += __shfl_down(a2, off, 64);
    if (lane==0) redb[wv] = a2;
    __syncthreads();                                   // B3
    double xn2 = redb[0]+redb[1]+redb[2]+redb[3];
    double alpha = sAlpha;
    double beta, tau, scl;
    if (xn2 == 0.0){ beta = alpha; tau = 0.0; scl = 0.0; }
    else {
      double nrm = sqrt(alpha*alpha + xn2);
      beta = (alpha >= 0.0) ? -nrm : nrm;              // dlarfg sign
      tau  = (beta - alpha)/beta;
      scl  = 1.0/(alpha - beta);
    }
    if (tid==0){
      if (bid==0){ tauv[k]=tau; betaH[k]=beta; }
      // diagonal fix by row-k OWNER: keeps the dirty line in one L2 only
      if (k>0 && bid == (k % HH_GRID)) Ah[(size_t)k*AH_LD + k] -= 2.0*wfull[k];
    }
    for (int j = k+1 + tid; j < 1000; j += 256)
      vk[j] = (j == k+1) ? 1.0 : vk[j]*scl;
    __syncthreads();                                   // B4: vk ready
    if (bid==0){
      for (int j = k+1 + tid; j < 1000; j += 256)
        Vh[(size_t)k*MF + j] = vk[j];
    }

    // ---- owned-row pass: apply update k-1, fused symv, stage col k+1 ----
    int r = myrow;
    if (r >= k+1 && r < 1000){
      double vr = (k>0)? vprev[r] : 0.0;
      double wr = (k>0)? wfull[r] : 0.0;
      double* row = Ah + (size_t)r*AH_LD;
      double acc = 0.0;
      for (int c = k+1 + lane; c < 1000; c += 64){
        double a = row[c];
        if (k > 0){ a -= vr*wfull[c] + wr*vprev[c]; row[c] = a; }
        acc += a*vk[c];
        if (c == k+1) cohStoreD(&colnext[r], a);
      }
      #pragma unroll
      for (int off=32; off; off>>=1) acc += __shfl_down(acc, off, 64);
      if (lane==0) cohStoreD(&w1next[r], acc);
    }

    grid_sync_fast(bar);
    tau_prev = tau;
  }
}

__device__ __forceinline__ int sgnchg(double a, double b){
  return (int)(((unsigned long long)(__double_as_longlong(a) ^ __double_as_longlong(b))) >> 63);
}

// ---- fin (trailing 2x2) + extract (diag/subdiag) + Sturm bisection, fused ----
__global__ void k_post(double* __restrict__ Ah, const double* __restrict__ Vh,
                       const double* __restrict__ tauv, const double* __restrict__ w1last,
                       double* __restrict__ alphaH, double* __restrict__ betaH,
                       double* __restrict__ lamT){
  __shared__ double al[1000], abv[1000], bb[1000];
  int tid = threadIdx.x;
  if (tid==0){
    double v8 = Vh[(size_t)997*MF + 998];   // == 1.0
    double v9 = Vh[(size_t)997*MF + 999];
    double w18 = w1last[998], w19 = w1last[999];
    double tau = tauv[997];
    double vdot = v8*w18 + v9*w19;
    double hts = 0.5*tau*tau*vdot;
    double w8 = tau*w18 - hts*v8;
    double w9 = tau*w19 - hts*v9;
    Ah[(size_t)998*AH_LD+998] -= v8*w8 + w8*v8;
    Ah[(size_t)999*AH_LD+998] -= v9*w8 + w9*v8;
    Ah[(size_t)999*AH_LD+999] -= v9*w9 + w9*v9;
  }
  __syncthreads();
  for (int t=tid;t<1000;t+=64){
    double a2 = Ah[(size_t)t*AH_LD+t];
    alphaH[t]=a2; al[t]=a2;
  }
  if (tid==0) betaH[998] = Ah[(size_t)999*AH_LD+998];
  __syncthreads();
  for (int t=tid;t<1000;t+=64){
    double b = (t<999)? betaH[t] : 0.0;
    abv[t]=fabs(b); bb[t]=b*b;
  }
  __syncthreads();
  if (tid >= NCOMP) return;
  int i = tid;
  double lo=1e300, hi=-1e300;
  for (int k2=0;k2<1000;k2++){
    double bl = (k2>0)? abv[k2-1] : 0.0;
    double br = (k2<999)? abv[k2] : 0.0;
    double a = al[k2];
    lo = fmin(lo, a-bl-br);
    hi = fmax(hi, a+bl+br);
  }
  int target = 999 - i;
  for (int it=0; it<55; it++){
    double mid = 0.5*(lo+hi);
    int cnt = 0;
    double d1 = 1.0;
    double d0 = al[0]-mid;
    cnt += (int)(((unsigned long long)__double_as_longlong(d0))>>63);
    int k2 = 1;
    for (; k2+3 < 1000; k2 += 4){
      double n0 = (al[k2  ]-mid)*d0 - bb[k2-1]*d1;
      double n1 = (al[k2+1]-mid)*n0 - bb[k2  ]*d0;
      double n2 = (al[k2+2]-mid)*n1 - bb[k2+1]*n0;
      double n3 = (al[k2+3]-mid)*n2 - bb[k2+2]*n1;
      cnt += sgnchg(n0,d0)+sgnchg(n1,n0)+sgnchg(n2,n1)+sgnchg(n3,n2);
      double mm = fmax(fabs(n3), fabs(n2));
      double s = (mm > 1e250) ? 1e-250 : ((mm < 1e-250) ? 1e250 : 1.0);
      d1 = n2*s; d0 = n3*s;
    }
    for (; k2 < 1000; k2++){
      double nn = (al[k2]-mid)*d0 - bb[k2-1]*d1;
      cnt += sgnchg(nn, d0);
      d1 = d0; d0 = nn;
    }
    if (cnt > target) hi = mid; else lo = mid;
  }
  lamT[i] = 0.5*(lo+hi);
}

// ---- serial pivoted tridiagonal solve (LAPACK dgtsv replica), thread-0 only ----
__device__ void gtsv_serial(int m, double* dl, double* dd, double* du, double* x){
  for (int r=0;r<m-1;r++){
    if (fabs(dd[r]) >= fabs(dl[r])){
      if (dd[r] != 0.0){
        double fact = dl[r]/dd[r];
        dd[r+1] -= fact*du[r];
        x[r+1]  -= fact*x[r];
      }
      if (r < m-2) dl[r] = 0.0;
    } else {
      double fact = dd[r]/dl[r];
      dd[r] = dl[r];
      double tdd = dd[r+1];
      dd[r+1] = du[r] - fact*tdd;
      if (r < m-2){
        double tdu = du[r+1];
        dl[r] = tdu;
        du[r+1] = -fact*tdu;
      }
      du[r] = tdd;
      double t2 = x[r]; x[r] = x[r+1]; x[r+1] = t2 - fact*x[r+1];
    }
  }
  x[m-1] /= dd[m-1];
  if (m >= 2) x[m-2] = (x[m-2] - du[m-2]*x[m-1])/dd[m-2];
  for (int r=m-3;r>=0;r--)
    x[r] = (x[r] - du[r]*x[r+1] - dl[r]*x[r+2])/dd[r];
}

// ---- inverse iteration + D&C sign replication, fused (one block per eigpair) ----
__global__ void __launch_bounds__(256) k_invsign(const double* __restrict__ alphaH,
                                                 const double* __restrict__ betaH,
                                                 const double* __restrict__ lamT,
                                                 double* __restrict__ V50,
                                                 float* __restrict__ sgnv){
  __shared__ double v[1000], xx[1000], dd[1000], du[1000], dl[1000];
  __shared__ double red[256];
  __shared__ double lam_s;
  __shared__ int ab[2];
  __shared__ float sig;
  int i = blockIdx.x, tid = threadIdx.x;
  double lam = lamT[i];
  for (int t=tid;t<1000;t+=256){
    unsigned h = wang((unsigned)(i*1000+t)*2654435761u + 777u);
    v[t] = (double)(h & 0xffffffu)/8388608.0 - 1.0;
  }
  __syncthreads();
  for (int it=0; it<3; it++){
    for (int t=tid;t<1000;t+=256){
      dd[t] = alphaH[t]-lam;
      if (t<999){ du[t]=betaH[t]; dl[t]=betaH[t]; }
      xx[t] = v[t];
    }
    __syncthreads();
    if (tid==0) gtsv_serial(1000, dl, dd, du, xx);
    __syncthreads();
    double a=0; for (int t=tid;t<1000;t+=256) a += xx[t]*xx[t];
    red[tid]=a; __syncthreads();
    for (int off=128;off;off>>=1){ if(tid<off) red[tid]+=red[tid+off]; __syncthreads(); }
    double inv = 1.0/sqrt(red[0]);
    __syncthreads();
    for (int t=tid;t<1000;t+=256) v[t]=xx[t]*inv;
    __syncthreads();
  }
  // Rayleigh quotient -> refined lambda (kept in LDS; no global round trip)
  double a=0;
  for (int t=tid;t<1000;t+=256){
    double s = alphaH[t]*v[t];
    if (t>0)   s += betaH[t-1]*v[t-1];
    if (t<999) s += betaH[t]*v[t+1];
    a += v[t]*s;
  }
  red[tid]=a; __syncthreads();
  for (int off=128;off;off>>=1){ if(tid<off) red[tid]+=red[tid+off]; __syncthreads(); }
  if (tid==0){ lam_s = red[0]; ab[0]=0; ab[1]=1000; sig=1.f; }
  for (int t=tid;t<1000;t+=256) V50[(size_t)i*1000+t]=v[t];
  __syncthreads();
  // ---- sign phase (operates on v in place; V50 already stored) ----
  while (true){
    int a0=ab[0], b0=ab[1];
    if (b0-a0 <= 25) break;
    int c = a0 + (b0-a0)/2;
    double m1=0,m2=0;
    for (int t=a0+tid;t<b0;t+=256){ double q=v[t]*v[t]; if (t<c) m1+=q; else m2+=q; }
    red[tid]=m1; __syncthreads();
    for (int off=128;off;off>>=1){ if(tid<off) red[tid]+=red[tid+off]; __syncthreads(); }
    double M1=red[0]; __syncthreads();
    red[tid]=m2; __syncthreads();
    for (int off=128;off;off>>=1){ if(tid<off) red[tid]+=red[tid+off]; __syncthreads(); }
    double M2=red[0]; __syncthreads();
    double tot=M1+M2;
    if (fmin(M1,M2) <= 1e-10*tot){
      if (tid==0){ if (M1>=M2) ab[1]=c; else ab[0]=c; }
      __syncthreads();
      a0=ab[0]; b0=ab[1];
      double nn=0; for (int t=a0+tid;t<b0;t+=256) nn+=v[t]*v[t];
      red[tid]=nn; __syncthreads();
      for (int off=128;off;off>>=1){ if(tid<off) red[tid]+=red[tid+off]; __syncthreads(); }
      double inv = 1.0/sqrt(red[0]); __syncthreads();
      for (int t=a0+tid;t<b0;t+=256) v[t]*=inv;
      __syncthreads();
      for (int it=0; it<2; it++){
        for (int t=a0+tid;t<b0;t+=256){
          int L=t-a0;
          dd[L]=alphaH[t]-lam_s;
          if (t<b0-1){ du[L]=betaH[t]; dl[L]=betaH[t]; }
          xx[L]=v[t];
        }
        __syncthreads();
        if (tid==0) gtsv_serial(b0-a0, dl, dd, du, xx);
        __syncthreads();
        double s2=0; for (int t=a0+tid;t<b0;t+=256){ double q=xx[t-a0]; s2+=q*q; }
        red[tid]=s2; __syncthreads();
        for (int off=128;off;off>>=1){ if(tid<off) red[tid]+=red[tid+off]; __syncthreads(); }
        double inv2 = 1.0/sqrt(red[0]); __syncthreads();
        for (int t=a0+tid;t<b0;t+=256) v[t]=xx[t-a0]*inv2;
        __syncthreads();
      }
      double rq=0;
      for (int t=a0+tid;t<b0;t+=256){
        double s = alphaH[t]*v[t];
        if (t>a0)   s += betaH[t-1]*v[t-1];
        if (t<b0-1) s += betaH[t]*v[t+1];
        rq += v[t]*s;
      }
      red[tid]=rq; __syncthreads();
      for (int off=128;off;off>>=1){ if(tid<off) red[tid]+=red[tid+off]; __syncthreads(); }
      if (tid==0) lam_s=red[0];
      __syncthreads();
      continue;
    }
    if (tid==0){
      double vc1 = v[c-1], vc = v[c];
      if (fabs(vc1) >= fabs(vc)){
        sig = (vc1 < 0.0) ? 1.f : -1.f;
      } else {
        double req = (betaH[c-1] >= 0.0) ? -1.0 : 1.0;
        double have = (vc >= 0.0) ? 1.0 : -1.0;
        sig = (have == req) ? 1.f : -1.f;
      }
    }
    break;
  }
  __syncthreads();
  if (tid==0) sgnv[i]=sig;
}

// ---- m_i = Q v_i (descending reflectors): u in registers, 1 barrier/reflector ----
__global__ void __launch_bounds__(256) k_applyQm(const double* __restrict__ Vh,
                                                 const double* __restrict__ tauv,
                                                 const double* __restrict__ V50,
                                                 const float* __restrict__ sgnv,
                                                 float* __restrict__ E50){
  __shared__ double red2[2][4];
  __shared__ double tl[1000];
  int i = blockIdx.x, tid = threadIdx.x;
  int lane = tid & 63, wv = tid >> 6;
  int base = tid*4;                        // thread owns u[base..base+3]
  for (int t=tid;t<1000;t+=256) tl[t] = tauv[t];
  const double* src = V50 + (size_t)i*1000;
  double u0=0,u1=0,u2=0,u3=0;
  if (base < 1000){
    u0 = src[base]; u1 = src[base+1]; u2 = src[base+2]; u3 = src[base+3];
  }
  __syncthreads();
  for (int k=997;k>=0;k--){
    const double* v = Vh + (size_t)k*MF;
    double a = 0.0, v0=0,v1=0,v2=0,v3=0;
    if (base < 1000 && base+3 >= k+1){
      if (base   >= k+1){ v0 = v[base  ]; a += v0*u0; }
      if (base+1 >= k+1){ v1 = v[base+1]; a += v1*u1; }
      if (base+2 >= k+1){ v2 = v[base+2]; a += v2*u2; }
      if (base+3 >= k+1){ v3 = v[base+3]; a += v3*u3; }
    }
    #pragma unroll
    for (int off=32; off; off>>=1) a += __shfl_down(a, off, 64);
    if (lane==0) red2[k&1][wv] = a;
    __syncthreads();
    double td = tl[k]*(red2[k&1][0]+red2[k&1][1]+red2[k&1][2]+red2[k&1][3]);
    u0 -= td*v0; u1 -= td*v1; u2 -= td*v2; u3 -= td*v3;
  }
  double s = (double)sgnv[i];
  if (base < 1000){
    E50[(size_t)(base  )*NCOMP + i] = (float)(u0*s);
    E50[(size_t)(base+1)*NCOMP + i] = (float)(u1*s);
    E50[(size_t)(base+2)*NCOMP + i] = (float)(u2*s);
    E50[(size_t)(base+3)*NCOMP + i] = (float)(u3*s);
  }
}

// ---------------- P = (x-mean) * E -> d_out pca region ----------------
__global__ void k_pca(const float* __restrict__ x, const float* __restrict__ mean,
                      const float* __restrict__ E, float* __restrict__ P){
  __shared__ float As[64][65];
  __shared__ float Es[64][65];
  int r0 = blockIdx.x*64;
  int tx = threadIdx.x & 15, ty = threadIdx.x >> 4;
  float acc[4][4];
  #pragma unroll
  for (int u=0;u<4;u++)
    #pragma unroll
    for (int v=0;v<4;v++) acc[u][v]=0.f;
  for (int k0=0;k0<MF;k0+=64){
    for (int t=threadIdx.x;t<64*64;t+=256){
      int i=t>>6, kk=t&63; int k=k0+kk;
      As[i][kk] = (k<MF) ? (x[(size_t)(r0+i)*MF+k]-mean[k]) : 0.f;
    }
    for (int t=threadIdx.x;t<64*65;t+=256){
      int kk=t/65, c=t%65; int k=k0+kk;
      Es[kk][c] = (k<MF && c<NCOMP) ? E[(size_t)k*NCOMP+c] : 0.f;
    }
    __syncthreads();
    for (int kk=0;kk<64;kk++){
      float a[4], b[4];
      #pragma unroll
      for (int u=0;u<4;u++){ a[u]=As[ty*4+u][kk]; b[u]=Es[kk][tx*4+u]; }
      #pragma unroll
      for (int u=0;u<4;u++)
        #pragma unroll
        for (int v=0;v<4;v++) acc[u][v] += a[u]*b[v];
    }
    __syncthreads();
  }
  #pragma unroll
  for (int u=0;u<4;u++){
    int r=r0+ty*4+u;
    #pragma unroll
    for (int v=0;v<4;v++){
      int c=tx*4+v;
      if (c<NCOMP) P[(size_t)r*NCOMP+c] = acc[u][v];
    }
  }
}

// ---------------- row squared norms ----------------
__global__ void k_rowsq(const float* __restrict__ P, float* __restrict__ sqv){
  int r = blockIdx.x*256 + threadIdx.x;
  if (r < NS){
    float s=0;
    for (int c=0;c<NCOMP;c++){ float v=P[(size_t)r*NCOMP+c]; s+=v*v; }
    sqv[r]=s;
  }
}

// ---------------- fused d2 + top-15 + transition row + diff weights ----------------
__global__ void k_knn(const float* __restrict__ P, const float* __restrict__ sqv,
                      float* __restrict__ trans, int* __restrict__ kidx,
                      float* __restrict__ kwd){
  __shared__ float pi[64];
  __shared__ unsigned long long keys[16*256];
  __shared__ unsigned long long redk[4];
  __shared__ unsigned long long wink[15];
  __shared__ float wt[15], wd[15], sums[2];
  int i = blockIdx.x, tid = threadIdx.x;
  int lane = tid & 63, wv = tid >> 6;
  for (int t=tid;t<NCOMP;t+=256) pi[t] = P[(size_t)i*NCOMP+t];
  __syncthreads();
  float sqi = sqv[i];
  for (int s2=0;s2<16;s2++){
    int j = tid + s2*256;
    float dot=0;
    for (int c=0;c<NCOMP;c++) dot += pi[c]*P[(size_t)j*NCOMP+c];
    float d2 = sqi + sqv[j] - 2.f*dot;
    d2 = fmaxf(d2, 0.f);
    unsigned int db = __float_as_uint(d2);
    keys[s2*256+tid] = ((unsigned long long)db<<32) | (unsigned)j;
  }
  __syncthreads();
  for (int rsel=0;rsel<15;rsel++){
    unsigned long long m = ~0ull;
    #pragma unroll
    for (int s2=0;s2<16;s2++){
      unsigned long long k = keys[s2*256+tid];
      m = (k<m)?k:m;
    }
    #pragma unroll
    for (int off=32; off; off>>=1){
      unsigned long long o = __shfl_down(m, off, 64);
      m = (o<m)?o:m;
    }
    if (lane==0) redk[wv]=m;
    __syncthreads();
    unsigned long long w = redk[0];
    if (redk[1]<w) w=redk[1];
    if (redk[2]<w) w=redk[2];
    if (redk[3]<w) w=redk[3];
    if (tid==0) wink[rsel]=w;
    #pragma unroll
    for (int s2=0;s2<16;s2++)
      if (keys[s2*256+tid]==w) keys[s2*256+tid]=~0ull;
    __syncthreads();
  }
  if (tid<15){
    unsigned long long w = wink[tid];
    float d2 = __uint_as_float((unsigned)(w>>32));
    wt[tid] = expf(-0.5f*d2);
    wd[tid] = expf(-d2);
  }
  __syncthreads();
  if (tid==0){
    float st=0, sd=0;
    for (int k=0;k<15;k++){ st+=wt[k]; sd+=wd[k]; }
    sums[0]=st; sums[1]=sd;
  }
  __syncthreads();
  float* row = trans + (size_t)i*NS;
  for (int c=tid;c<NS;c+=256) row[c]=0.f;
  __syncthreads();
  if (tid<15){
    int j = (int)(wink[tid] & 0xffffffffull);
    row[j] = wt[tid]/sums[0];
    kidx[i*15+tid] = j;
    kwd[i*15+tid]  = wd[tid]/sums[1];
  }
}

// ---------------- 100-iteration sparse power iteration ----------------
__global__ void __launch_bounds__(1024) k_power(const int* __restrict__ kidx,
                                                const float* __restrict__ kwd,
                                                float* __restrict__ outPT){
  __shared__ float d[4096];
  __shared__ float dn[4096];
  __shared__ float red[16];
  int tid = threadIdx.x;
  int lane = tid & 63, wv = tid >> 6;
  for (int t=tid;t<4096;t+=1024) d[t] = (t==0)?1.f:0.f;
  __syncthreads();
  for (int it=0; it<100; it++){
    float lmax = 0.f;
    for (int r=tid;r<4096;r+=1024){
      float a=0;
      #pragma unroll
      for (int k=0;k<15;k++) a += kwd[r*15+k]*d[kidx[r*15+k]];
      dn[r]=a;
      lmax = fmaxf(lmax, a);
    }
    #pragma unroll
    for (int off=32; off; off>>=1) lmax = fmaxf(lmax, __shfl_down(lmax, off, 64));
    if (lane==0) red[wv]=lmax;
    __syncthreads();
    float m = red[0];
    #pragma unroll
    for (int w=1;w<16;w++) m = fmaxf(m, red[w]);
    for (int r=tid;r<4096;r+=1024) d[r]=dn[r]/m;
    __syncthreads();
  }
  for (int t=tid;t<4096;t+=1024) outPT[t]=d[t];
}

// ---------------- host ----------------
// Footprint ~17.11 MB (< 22.42 MB proven). Ah (padded 1000x1024 fp64) dies
// after k_post; sqv/kidx/kwd overlay it.
extern "C" void kernel_launch(void* const* d_in, const int* in_sizes, int n_in,
                              void* d_out, int out_size, void* d_ws, size_t ws_size,
                              hipStream_t stream){
  const float* x = (const float*)d_in[0];
  float* out = (float*)d_out;
  char* base = (char*)d_ws;

  double* Ah     = (double*)(base + 0);            // 8,192,000 (dead after k_post)
  float*  sqv    = (float*) (base + 0);            //    16,384 overlay
  int*    kidx   = (int*)   (base + 16384);        //   245,760 overlay
  float*  kwd    = (float*) (base + 262144);       //   245,760 overlay (ends 507,904)
  double* Vh     = (double*)(base + 8192000);      // 8,000,000
  double* V50    = (double*)(base + 16192000);     //   400,000
  float*  E50    = (float*) (base + 16592000);     //   200,000
  float*  part   = (float*) (base + 16792000);     //   256,000
  float*  mean   = (float*) (base + 17048000);     //     4,000
  double* tauv   = (double*)(base + 17052000);     //     8,000
  double* betaH  = (double*)(base + 17060000);     //     8,000
  double* alphaH = (double*)(base + 17068000);     //     8,000
  double* w1a    = (double*)(base + 17076000);     //     8,000
  double* w1b    = (double*)(base + 17084000);     //     8,000
  double* cola   = (double*)(base + 17092000);     //     8,000
  double* colb   = (double*)(base + 17100000);     //     8,000
  double* lamT   = (double*)(base + 17108000);     //       400
  float*  sgnv   = (float*) (base + 17108400);     //       200
  unsigned long long* bar = (unsigned long long*)(base + 17108600); // 8

  k_colsum<<<64,256,0,stream>>>(x, part);
  k_colmean<<<4,256,0,stream>>>(part, mean);
  k_barinit<<<1,64,0,stream>>>(bar);
  k_cov<<<dim3(16,16),dim3(16,16),0,stream>>>(x, mean, Ah);

  // persistent fp64 Householder tridiagonalization (single launch, 998 steps)
  k_hh_all<<<HH_GRID,256,0,stream>>>(Ah, Vh, tauv, betaH, w1a, w1b, cola, colb, bar);

  // fin + extract + top-50 Sturm bisection
  k_post<<<1,64,0,stream>>>(Ah, Vh, tauv, w1b, alphaH, betaH, lamT);

  // inverse iteration + D&C sign replication (fused)
  k_invsign<<<50,256,0,stream>>>(alphaH, betaH, lamT, V50, sgnv);

  // back-transform + sign -> eigenvectors, then outputs
  k_applyQm<<<50,256,0,stream>>>(Vh, tauv, V50, sgnv, E50);
  k_pca<<<64,256,0,stream>>>(x, mean, E50, out + PCA_OFF);
  k_rowsq<<<16,256,0,stream>>>(out + PCA_OFF, sqv);
  k_knn<<<4096,256,0,stream>>>(out + PCA_OFF, sqv, out + TR_OFF, kidx, kwd);
  k_power<<<1,1024,0,stream>>>(kidx, kwd, out);
}

// Round 5
// 14843.507 us; speedup vs baseline: 2.6615x; 1.1681x over previous
//
#include <hip/hip_runtime.h>
#include <math.h>
#include <stdint.h>

// ---- problem constants ----
static const int NS = 4096;    // samples
static const int MF = 1000;    // features
static const int NCOMP = 50;   // principal components
#define AH_LD 1024             // padded Ah leading dim: rows = 64 full cachelines,
                               // no line shared between two owner blocks

// out layout: pseudotime [4096] | transition [4096*4096] | pca [4096*50]
#define TR_OFF  ((size_t)4096)
#define PCA_OFF ((size_t)4096 + (size_t)4096*4096)
#define HH_GRID 250

// ---------------- column mean ----------------
__global__ void k_colsum(const float* __restrict__ x, float* __restrict__ part){
  int b = blockIdx.x, tid = threadIdx.x;
  float a0=0,a1=0,a2=0,a3=0;
  for (int r=b*64; r<b*64+64; r++){
    const float* row = x + (size_t)r*MF;
    if (tid      < MF) a0 += row[tid];
    if (tid+256  < MF) a1 += row[tid+256];
    if (tid+512  < MF) a2 += row[tid+512];
    if (tid+768  < MF) a3 += row[tid+768];
  }
  if (tid      < MF) part[b*MF+tid]     = a0;
  if (tid+256  < MF) part[b*MF+tid+256] = a1;
  if (tid+512  < MF) part[b*MF+tid+512] = a2;
  if (tid+768  < MF) part[b*MF+tid+768] = a3;
}

__global__ void k_colmean(const float* __restrict__ part, float* __restrict__ mean){
  int c = blockIdx.x*256 + threadIdx.x;
  if (c < MF){ float s=0; for (int b=0;b<64;b++) s += part[b*MF+c]; mean[c] = s/4096.0f; }
}

// zero the per-block flags (64B-padded) and the generation counter
__global__ void k_barinit(unsigned* flags, unsigned* gen){
  int t = threadIdx.x;
  if (t < HH_GRID) flags[t*16] = 0u;
  if (t == 255) *gen = 0u;
}

// ---------------- cov = (x-mean)^T (x-mean) / (n-1), fp64 out ----------------
// Lower-triangle blocks only; mirror write (bitwise-identical values).
__global__ void k_cov(const float* __restrict__ x, const float* __restrict__ mean,
                      double* __restrict__ Ah){
  __shared__ float As[32][65];
  __shared__ float Bs[32][65];
  int bx = blockIdx.x, by = blockIdx.y;
  if (bx > by) return;
  int i0 = by*64, j0 = bx*64;
  int tx = threadIdx.x, ty = threadIdx.y;
  int tid = ty*16+tx;
  double acc[4][4];
  #pragma unroll
  for (int u=0;u<4;u++)
    #pragma unroll
    for (int v=0;v<4;v++) acc[u][v]=0.0;
  for (int k0=0;k0<4096;k0+=32){
    for (int t=tid;t<32*64;t+=256){
      int kk=t>>6, ii=t&63;
      int gi=i0+ii, gj=j0+ii;
      As[kk][ii] = (gi<MF) ? (x[(size_t)(k0+kk)*MF+gi]-mean[gi]) : 0.f;
      Bs[kk][ii] = (gj<MF) ? (x[(size_t)(k0+kk)*MF+gj]-mean[gj]) : 0.f;
    }
    __syncthreads();
    for (int kk=0;kk<32;kk++){
      float a[4], b[4];
      #pragma unroll
      for (int u=0;u<4;u++){ a[u]=As[kk][ty*4+u]; b[u]=Bs[kk][tx*4+u]; }
      #pragma unroll
      for (int u=0;u<4;u++)
        #pragma unroll
        for (int v=0;v<4;v++) acc[u][v] += (double)a[u]*(double)b[v];
    }
    __syncthreads();
  }
  #pragma unroll
  for (int u=0;u<4;u++)
    #pragma unroll
    for (int v=0;v<4;v++){
      int gi=i0+ty*4+u, gj=j0+tx*4+v;
      if (gi<MF && gj<MF){
        double val = acc[u][v]*(1.0/4095.0);
        Ah[(size_t)gi*AH_LD+gj] = val;
        Ah[(size_t)gj*AH_LD+gi] = val;
      }
    }
}

__device__ __forceinline__ unsigned wang(unsigned s){
  s=(s^61u)^(s>>16); s*=9u; s^=s>>4; s*=0x27d4eb2du; s^=s>>15; return s;
}

// ---- device-coherent (agent-scope, relaxed) load/store helpers ----
__device__ __forceinline__ double cohLoadD(const double* p){
  unsigned long long v = __hip_atomic_load((const unsigned long long*)p,
      __ATOMIC_RELAXED, __HIP_MEMORY_SCOPE_AGENT);
  return __longlong_as_double((long long)v);
}
__device__ __forceinline__ void cohStoreD(double* p, double v){
  __hip_atomic_store((unsigned long long*)p,
      (unsigned long long)__double_as_longlong(v),
      __ATOMIC_RELAXED, __HIP_MEMORY_SCOPE_AGENT);
}
__device__ __forceinline__ unsigned cohLoadU(const unsigned* p){
  return __hip_atomic_load(p, __ATOMIC_RELAXED, __HIP_MEMORY_SCOPE_AGENT);
}
__device__ __forceinline__ void cohStoreU(unsigned* p, unsigned v){
  __hip_atomic_store(p, v, __ATOMIC_RELAXED, __HIP_MEMORY_SCOPE_AGENT);
}

// ======== persistent fp64 Householder tridiagonalization (all 998 steps) ====
// Fixed row ownership: wave wv of block b owns row r = b + 250*wv forever ->
// Ah rows stay dirty in the owner's XCD L2, never cross XCDs. Only w1/col
// (8KB each) cross blocks, via agent-scope write-through.
// Grid barrier: contention-free flag array (one 64B line per block) scanned
// by block 0 wave 0 (its owned row 0 is dead for every k, so it's free),
// which publishes a generation counter. No same-line atomic pileup.
// Arithmetic + reduction orders bitwise-identical to the verified version.
__global__ void __launch_bounds__(256) k_hh_all(double* Ah,
                                                double* __restrict__ Vh,
                                                double* __restrict__ tauv,
                                                double* __restrict__ betaH,
                                                double* w1a, double* w1b,
                                                double* cola, double* colb,
                                                unsigned* flags, unsigned* gen){
  __shared__ double vbuf[2][1000];
  __shared__ double wfull[1000];
  __shared__ double red4[4], redb[4];
  __shared__ double sAlpha;
  int tid = threadIdx.x;
  int lane = tid & 63, wv = tid >> 6;
  int bid = blockIdx.x;
  int myrow = bid + wv*HH_GRID;           // fixed ownership (wave-level)
  double tau_prev = 0.0;

  for (int k = 0; k < 998; k++){
    double* vk    = vbuf[k & 1];
    double* vprev = vbuf[(k & 1) ^ 1];
    const double* w1prev  = (k & 1) ? w1a : w1b;
    double*       w1next  = (k & 1) ? w1b : w1a;
    const double* colprev = (k & 1) ? cola : colb;
    double*       colnext = (k & 1) ? colb : cola;

    // ---- prologue: vdot = v_{k-1}^T w1_{k-1}; wfull = tau*w1 - hts*v ----
    double vd = 0.0;
    if (k > 0){
      for (int j = k + tid; j < 1000; j += 256){
        double ww = cohLoadD(&w1prev[j]);
        wfull[j] = ww;
        vd += vprev[j]*ww;
      }
    }
    #pragma unroll
    for (int off=32; off; off>>=1) vd += __shfl_down(vd, off, 64);
    if (lane==0) red4[wv] = vd;
    __syncthreads();                                   // B1
    double vdot = red4[0]+red4[1]+red4[2]+red4[3];
    double tp  = tau_prev;
    double hts = 0.5*tp*tp*vdot;
    if (k > 0){
      for (int j = k + tid; j < 1000; j += 256)
        wfull[j] = tp*wfull[j] - hts*vprev[j];
    }
    __syncthreads();                                   // B2: wfull ready

    // ---- updated column k -> vk[], alpha & tail norm ----
    double a2 = 0.0;
    for (int j = k+1 + tid; j < 1000; j += 256){
      double c;
      if (k > 0) c = cohLoadD(&colprev[j]) - (vprev[j]*wfull[k] + wfull[j]*vprev[k]);
      else       c = Ah[(size_t)j*AH_LD + k];
      vk[j] = c;
      if (j == k+1) sAlpha = c;          // tid 0; race-free alpha staging
      if (j > k+1) a2 += c*c;
    }
    #pragma unroll
    for (int off=32; off; off>>=1) a2 += __shfl_down(a2, off, 64);
    if (lane==0) redb[wv] = a2;
    __syncthreads();                                   // B3
    double xn2 = redb[0]+redb[1]+redb[2]+redb[3];
    double alpha = sAlpha;
    double beta, tau, scl;
    if (xn2 == 0.0){ beta = alpha; tau = 0.0; scl = 0.0; }
    else {
      double nrm = sqrt(alpha*alpha + xn2);
      beta = (alpha >= 0.0) ? -nrm : nrm;              // dlarfg sign
      tau  = (beta - alpha)/beta;
      scl  = 1.0/(alpha - beta);
    }
    if (tid==0){
      if (bid==0){ tauv[k]=tau; betaH[k]=beta; }
      // diagonal fix by row-k OWNER: keeps the dirty line in one L2 only
      if (k>0 && bid == (k % HH_GRID)) Ah[(size_t)k*AH_LD + k] -= 2.0*wfull[k];
    }
    for (int j = k+1 + tid; j < 1000; j += 256)
      vk[j] = (j == k+1) ? 1.0 : vk[j]*scl;
    __syncthreads();                                   // B4: vk ready
    if (bid==0){
      for (int j = k+1 + tid; j < 1000; j += 256)
        Vh[(size_t)k*MF + j] = vk[j];
    }

    // ---- owned-row pass: apply update k-1, fused symv, stage col k+1 ----
    int r = myrow;
    if (r >= k+1 && r < 1000){
      double vr = (k>0)? vprev[r] : 0.0;
      double wr = (k>0)? wfull[r] : 0.0;
      double* row = Ah + (size_t)r*AH_LD;
      double acc = 0.0;
      for (int c = k+1 + lane; c < 1000; c += 64){
        double a = row[c];
        if (k > 0){ a -= vr*wfull[c] + wr*vprev[c]; row[c] = a; }
        acc += a*vk[c];
        if (c == k+1) cohStoreD(&colnext[r], a);
      }
      #pragma unroll
      for (int off=32; off; off>>=1) acc += __shfl_down(acc, off, 64);
      if (lane==0) cohStoreD(&w1next[r], acc);
    }

    // ---- grid barrier (skip after last step; kernel end is the sync) ----
    if (k < 997){
      unsigned target = (unsigned)(k+1);
      asm volatile("s_waitcnt vmcnt(0)" ::: "memory");  // drain this wave's stores
      __syncthreads();                                   // all waves drained
      if (bid == 0){
        if (wv == 0){
          for(;;){
            unsigned mn = 0xffffffffu;
            for (int b = 1 + lane; b < HH_GRID; b += 64){
              unsigned f = cohLoadU(&flags[b*16]);
              if (f < mn) mn = f;
            }
            #pragma unroll
            for (int off=32; off; off>>=1){
              unsigned o = (unsigned)__shfl_down((int)mn, off, 64);
              if (o < mn) mn = o;
            }
            mn = (unsigned)__shfl((int)mn, 0, 64);       // broadcast lane0 min
            if (mn >= target) break;
            __builtin_amdgcn_s_sleep(1);
          }
          if (lane==0) cohStoreU(gen, target);
        }
        __syncthreads();
      } else {
        if (tid==0){
          cohStoreU(&flags[bid*16], target);
          while (cohLoadU(gen) < target) __builtin_amdgcn_s_sleep(1);
        }
        __syncthreads();
      }
    }
    tau_prev = tau;
  }
}

__device__ __forceinline__ int sgnchg(double a, double b){
  return (int)(((unsigned long long)(__double_as_longlong(a) ^ __double_as_longlong(b))) >> 63);
}

// ---- fin (trailing 2x2) + extract (diag/subdiag) + Sturm bisection, fused ----
__global__ void k_post(double* __restrict__ Ah, const double* __restrict__ Vh,
                       const double* __restrict__ tauv, const double* __restrict__ w1last,
                       double* __restrict__ alphaH, double* __restrict__ betaH,
                       double* __restrict__ lamT){
  __shared__ double al[1000], abv[1000], bb[1000];
  int tid = threadIdx.x;
  if (tid==0){
    double v8 = Vh[(size_t)997*MF + 998];   // == 1.0
    double v9 = Vh[(size_t)997*MF + 999];
    double w18 = w1last[998], w19 = w1last[999];
    double tau = tauv[997];
    double vdot = v8*w18 + v9*w19;
    double hts = 0.5*tau*tau*vdot;
    double w8 = tau*w18 - hts*v8;
    double w9 = tau*w19 - hts*v9;
    Ah[(size_t)998*AH_LD+998] -= v8*w8 + w8*v8;
    Ah[(size_t)999*AH_LD+998] -= v9*w8 + w9*v8;
    Ah[(size_t)999*AH_LD+999] -= v9*w9 + w9*v9;
  }
  __syncthreads();
  for (int t=tid;t<1000;t+=64){
    double a2 = Ah[(size_t)t*AH_LD+t];
    alphaH[t]=a2; al[t]=a2;
  }
  if (tid==0) betaH[998] = Ah[(size_t)999*AH_LD+998];
  __syncthreads();
  for (int t=tid;t<1000;t+=64){
    double b = (t<999)? betaH[t] : 0.0;
    abv[t]=fabs(b); bb[t]=b*b;
  }
  __syncthreads();
  if (tid >= NCOMP) return;
  int i = tid;
  double lo=1e300, hi=-1e300;
  for (int k2=0;k2<1000;k2++){
    double bl = (k2>0)? abv[k2-1] : 0.0;
    double br = (k2<999)? abv[k2] : 0.0;
    double a = al[k2];
    lo = fmin(lo, a-bl-br);
    hi = fmax(hi, a+bl+br);
  }
  int target = 999 - i;
  for (int it=0; it<55; it++){
    double mid = 0.5*(lo+hi);
    int cnt = 0;
    double d1 = 1.0;
    double d0 = al[0]-mid;
    cnt += (int)(((unsigned long long)__double_as_longlong(d0))>>63);
    int k2 = 1;
    for (; k2+3 < 1000; k2 += 4){
      double n0 = (al[k2  ]-mid)*d0 - bb[k2-1]*d1;
      double n1 = (al[k2+1]-mid)*n0 - bb[k2  ]*d0;
      double n2 = (al[k2+2]-mid)*n1 - bb[k2+1]*n0;
      double n3 = (al[k2+3]-mid)*n2 - bb[k2+2]*n1;
      cnt += sgnchg(n0,d0)+sgnchg(n1,n0)+sgnchg(n2,n1)+sgnchg(n3,n2);
      double mm = fmax(fabs(n3), fabs(n2));
      double s = (mm > 1e250) ? 1e-250 : ((mm < 1e-250) ? 1e250 : 1.0);
      d1 = n2*s; d0 = n3*s;
    }
    for (; k2 < 1000; k2++){
      double nn = (al[k2]-mid)*d0 - bb[k2-1]*d1;
      cnt += sgnchg(nn, d0);
      d1 = d0; d0 = nn;
    }
    if (cnt > target) hi = mid; else lo = mid;
  }
  lamT[i] = 0.5*(lo+hi);
}

// ---- serial pivoted tridiagonal solve (LAPACK dgtsv replica), thread-0 only ----
__device__ void gtsv_serial(int m, double* dl, double* dd, double* du, double* x){
  for (int r=0;r<m-1;r++){
    if (fabs(dd[r]) >= fabs(dl[r])){
      if (dd[r] != 0.0){
        double fact = dl[r]/dd[r];
        dd[r+1] -= fact*du[r];
        x[r+1]  -= fact*x[r];
      }
      if (r < m-2) dl[r] = 0.0;
    } else {
      double fact = dd[r]/dl[r];
      dd[r] = dl[r];
      double tdd = dd[r+1];
      dd[r+1] = du[r] - fact*tdd;
      if (r < m-2){
        double tdu = du[r+1];
        dl[r] = tdu;
        du[r+1] = -fact*tdu;
      }
      du[r] = tdd;
      double t2 = x[r]; x[r] = x[r+1]; x[r+1] = t2 - fact*x[r+1];
    }
  }
  x[m-1] /= dd[m-1];
  if (m >= 2) x[m-2] = (x[m-2] - du[m-2]*x[m-1])/dd[m-2];
  for (int r=m-3;r>=0;r--)
    x[r] = (x[r] - du[r]*x[r+1] - dl[r]*x[r+2])/dd[r];
}

// ---- inverse iteration + D&C sign replication, fused (one block per eigpair) ----
__global__ void __launch_bounds__(256) k_invsign(const double* __restrict__ alphaH,
                                                 const double* __restrict__ betaH,
                                                 const double* __restrict__ lamT,
                                                 double* __restrict__ V50,
                                                 float* __restrict__ sgnv){
  __shared__ double v[1000], xx[1000], dd[1000], du[1000], dl[1000];
  __shared__ double red[256];
  __shared__ double lam_s;
  __shared__ int ab[2];
  __shared__ float sig;
  int i = blockIdx.x, tid = threadIdx.x;
  double lam = lamT[i];
  for (int t=tid;t<1000;t+=256){
    unsigned h = wang((unsigned)(i*1000+t)*2654435761u + 777u);
    v[t] = (double)(h & 0xffffffu)/8388608.0 - 1.0;
  }
  __syncthreads();
  for (int it=0; it<3; it++){
    for (int t=tid;t<1000;t+=256){
      dd[t] = alphaH[t]-lam;
      if (t<999){ du[t]=betaH[t]; dl[t]=betaH[t]; }
      xx[t] = v[t];
    }
    __syncthreads();
    if (tid==0) gtsv_serial(1000, dl, dd, du, xx);
    __syncthreads();
    double a=0; for (int t=tid;t<1000;t+=256) a += xx[t]*xx[t];
    red[tid]=a; __syncthreads();
    for (int off=128;off;off>>=1){ if(tid<off) red[tid]+=red[tid+off]; __syncthreads(); }
    double inv = 1.0/sqrt(red[0]);
    __syncthreads();
    for (int t=tid;t<1000;t+=256) v[t]=xx[t]*inv;
    __syncthreads();
  }
  // Rayleigh quotient -> refined lambda (kept in LDS; no global round trip)
  double a=0;
  for (int t=tid;t<1000;t+=256){
    double s = alphaH[t]*v[t];
    if (t>0)   s += betaH[t-1]*v[t-1];
    if (t<999) s += betaH[t]*v[t+1];
    a += v[t]*s;
  }
  red[tid]=a; __syncthreads();
  for (int off=128;off;off>>=1){ if(tid<off) red[tid]+=red[tid+off]; __syncthreads(); }
  if (tid==0){ lam_s = red[0]; ab[0]=0; ab[1]=1000; sig=1.f; }
  for (int t=tid;t<1000;t+=256) V50[(size_t)i*1000+t]=v[t];
  __syncthreads();
  // ---- sign phase (operates on v in place; V50 already stored) ----
  while (true){
    int a0=ab[0], b0=ab[1];
    if (b0-a0 <= 25) break;
    int c = a0 + (b0-a0)/2;
    double m1=0,m2=0;
    for (int t=a0+tid;t<b0;t+=256){ double q=v[t]*v[t]; if (t<c) m1+=q; else m2+=q; }
    red[tid]=m1; __syncthreads();
    for (int off=128;off;off>>=1){ if(tid<off) red[tid]+=red[tid+off]; __syncthreads(); }
    double M1=red[0]; __syncthreads();
    red[tid]=m2; __syncthreads();
    for (int off=128;off;off>>=1){ if(tid<off) red[tid]+=red[tid+off]; __syncthreads(); }
    double M2=red[0]; __syncthreads();
    double tot=M1+M2;
    if (fmin(M1,M2) <= 1e-10*tot){
      if (tid==0){ if (M1>=M2) ab[1]=c; else ab[0]=c; }
      __syncthreads();
      a0=ab[0]; b0=ab[1];
      double nn=0; for (int t=a0+tid;t<b0;t+=256) nn+=v[t]*v[t];
      red[tid]=nn; __syncthreads();
      for (int off=128;off;off>>=1){ if(tid<off) red[tid]+=red[tid+off]; __syncthreads(); }
      double inv = 1.0/sqrt(red[0]); __syncthreads();
      for (int t=a0+tid;t<b0;t+=256) v[t]*=inv;
      __syncthreads();
      for (int it=0; it<2; it++){
        for (int t=a0+tid;t<b0;t+=256){
          int L=t-a0;
          dd[L]=alphaH[t]-lam_s;
          if (t<b0-1){ du[L]=betaH[t]; dl[L]=betaH[t]; }
          xx[L]=v[t];
        }
        __syncthreads();
        if (tid==0) gtsv_serial(b0-a0, dl, dd, du, xx);
        __syncthreads();
        double s2=0; for (int t=a0+tid;t<b0;t+=256){ double q=xx[t-a0]; s2+=q*q; }
        red[tid]=s2; __syncthreads();
        for (int off=128;off;off>>=1){ if(tid<off) red[tid]+=red[tid+off]; __syncthreads(); }
        double inv2 = 1.0/sqrt(red[0]); __syncthreads();
        for (int t=a0+tid;t<b0;t+=256) v[t]=xx[t-a0]*inv2;
        __syncthreads();
      }
      double rq=0;
      for (int t=a0+tid;t<b0;t+=256){
        double s = alphaH[t]*v[t];
        if (t>a0)   s += betaH[t-1]*v[t-1];
        if (t<b0-1) s += betaH[t]*v[t+1];
        rq += v[t]*s;
      }
      red[tid]=rq; __syncthreads();
      for (int off=128;off;off>>=1){ if(tid<off) red[tid]+=red[tid+off]; __syncthreads(); }
      if (tid==0) lam_s=red[0];
      __syncthreads();
      continue;
    }
    if (tid==0){
      double vc1 = v[c-1], vc = v[c];
      if (fabs(vc1) >= fabs(vc)){
        sig = (vc1 < 0.0) ? 1.f : -1.f;
      } else {
        double req = (betaH[c-1] >= 0.0) ? -1.0 : 1.0;
        double have = (vc >= 0.0) ? 1.0 : -1.0;
        sig = (have == req) ? 1.f : -1.f;
      }
    }
    break;
  }
  __syncthreads();
  if (tid==0) sgnv[i]=sig;
}

// ---- m_i = Q v_i (descending reflectors): u in registers, 1 barrier/reflector ----
__global__ void __launch_bounds__(256) k_applyQm(const double* __restrict__ Vh,
                                                 const double* __restrict__ tauv,
                                                 const double* __restrict__ V50,
                                                 const float* __restrict__ sgnv,
                                                 float* __restrict__ E50){
  __shared__ double red2[2][4];
  __shared__ double tl[1000];
  int i = blockIdx.x, tid = threadIdx.x;
  int lane = tid & 63, wv = tid >> 6;
  int base = tid*4;                        // thread owns u[base..base+3]
  for (int t=tid;t<1000;t+=256) tl[t] = tauv[t];
  const double* src = V50 + (size_t)i*1000;
  double u0=0,u1=0,u2=0,u3=0;
  if (base < 1000){
    u0 = src[base]; u1 = src[base+1]; u2 = src[base+2]; u3 = src[base+3];
  }
  __syncthreads();
  for (int k=997;k>=0;k--){
    const double* v = Vh + (size_t)k*MF;
    double a = 0.0, v0=0,v1=0,v2=0,v3=0;
    if (base < 1000 && base+3 >= k+1){
      if (base   >= k+1){ v0 = v[base  ]; a += v0*u0; }
      if (base+1 >= k+1){ v1 = v[base+1]; a += v1*u1; }
      if (base+2 >= k+1){ v2 = v[base+2]; a += v2*u2; }
      if (base+3 >= k+1){ v3 = v[base+3]; a += v3*u3; }
    }
    #pragma unroll
    for (int off=32; off; off>>=1) a += __shfl_down(a, off, 64);
    if (lane==0) red2[k&1][wv] = a;
    __syncthreads();
    double td = tl[k]*(red2[k&1][0]+red2[k&1][1]+red2[k&1][2]+red2[k&1][3]);
    u0 -= td*v0; u1 -= td*v1; u2 -= td*v2; u3 -= td*v3;
  }
  double s = (double)sgnv[i];
  if (base < 1000){
    E50[(size_t)(base  )*NCOMP + i] = (float)(u0*s);
    E50[(size_t)(base+1)*NCOMP + i] = (float)(u1*s);
    E50[(size_t)(base+2)*NCOMP + i] = (float)(u2*s);
    E50[(size_t)(base+3)*NCOMP + i] = (float)(u3*s);
  }
}

// ---------------- P = (x-mean) * E -> d_out pca region ----------------
__global__ void k_pca(const float* __restrict__ x, const float* __restrict__ mean,
                      const float* __restrict__ E, float* __restrict__ P){
  __shared__ float As[64][65];
  __shared__ float Es[64][65];
  int r0 = blockIdx.x*64;
  int tx = threadIdx.x & 15, ty = threadIdx.x >> 4;
  float acc[4][4];
  #pragma unroll
  for (int u=0;u<4;u++)
    #pragma unroll
    for (int v=0;v<4;v++) acc[u][v]=0.f;
  for (int k0=0;k0<MF;k0+=64){
    for (int t=threadIdx.x;t<64*64;t+=256){
      int i=t>>6, kk=t&63; int k=k0+kk;
      As[i][kk] = (k<MF) ? (x[(size_t)(r0+i)*MF+k]-mean[k]) : 0.f;
    }
    for (int t=threadIdx.x;t<64*65;t+=256){
      int kk=t/65, c=t%65; int k=k0+kk;
      Es[kk][c] = (k<MF && c<NCOMP) ? E[(size_t)k*NCOMP+c] : 0.f;
    }
    __syncthreads();
    for (int kk=0;kk<64;kk++){
      float a[4], b[4];
      #pragma unroll
      for (int u=0;u<4;u++){ a[u]=As[ty*4+u][kk]; b[u]=Es[kk][tx*4+u]; }
      #pragma unroll
      for (int u=0;u<4;u++)
        #pragma unroll
        for (int v=0;v<4;v++) acc[u][v] += a[u]*b[v];
    }
    __syncthreads();
  }
  #pragma unroll
  for (int u=0;u<4;u++){
    int r=r0+ty*4+u;
    #pragma unroll
    for (int v=0;v<4;v++){
      int c=tx*4+v;
      if (c<NCOMP) P[(size_t)r*NCOMP+c] = acc[u][v];
    }
  }
}

// ---------------- row squared norms ----------------
__global__ void k_rowsq(const float* __restrict__ P, float* __restrict__ sqv){
  int r = blockIdx.x*256 + threadIdx.x;
  if (r < NS){
    float s=0;
    for (int c=0;c<NCOMP;c++){ float v=P[(size_t)r*NCOMP+c]; s+=v*v; }
    sqv[r]=s;
  }
}

// ---------------- fused d2 + top-15 + transition row + diff weights ----------------
// kidx/kwd are PADDED to stride 16 (slot 15 = {0, 0.f}) for vectorized k_power.
__global__ void k_knn(const float* __restrict__ P, const float* __restrict__ sqv,
                      float* __restrict__ trans, int* __restrict__ kidx,
                      float* __restrict__ kwd){
  __shared__ float pi[64];
  __shared__ unsigned long long keys[16*256];
  __shared__ unsigned long long redk[4];
  __shared__ unsigned long long wink[15];
  __shared__ float wt[15], wd[15], sums[2];
  int i = blockIdx.x, tid = threadIdx.x;
  int lane = tid & 63, wv = tid >> 6;
  for (int t=tid;t<NCOMP;t+=256) pi[t] = P[(size_t)i*NCOMP+t];
  __syncthreads();
  float sqi = sqv[i];
  for (int s2=0;s2<16;s2++){
    int j = tid + s2*256;
    float dot=0;
    for (int c=0;c<NCOMP;c++) dot += pi[c]*P[(size_t)j*NCOMP+c];
    float d2 = sqi + sqv[j] - 2.f*dot;
    d2 = fmaxf(d2, 0.f);
    unsigned int db = __float_as_uint(d2);
    keys[s2*256+tid] = ((unsigned long long)db<<32) | (unsigned)j;
  }
  __syncthreads();
  for (int rsel=0;rsel<15;rsel++){
    unsigned long long m = ~0ull;
    #pragma unroll
    for (int s2=0;s2<16;s2++){
      unsigned long long k = keys[s2*256+tid];
      m = (k<m)?k:m;
    }
    #pragma unroll
    for (int off=32; off; off>>=1){
      unsigned long long o = __shfl_down(m, off, 64);
      m = (o<m)?o:m;
    }
    if (lane==0) redk[wv]=m;
    __syncthreads();
    unsigned long long w = redk[0];
    if (redk[1]<w) w=redk[1];
    if (redk[2]<w) w=redk[2];
    if (redk[3]<w) w=redk[3];
    if (tid==0) wink[rsel]=w;
    #pragma unroll
    for (int s2=0;s2<16;s2++)
      if (keys[s2*256+tid]==w) keys[s2*256+tid]=~0ull;
    __syncthreads();
  }
  if (tid<15){
    unsigned long long w = wink[tid];
    float d2 = __uint_as_float((unsigned)(w>>32));
    wt[tid] = expf(-0.5f*d2);
    wd[tid] = expf(-d2);
  }
  __syncthreads();
  if (tid==0){
    float st=0, sd=0;
    for (int k=0;k<15;k++){ st+=wt[k]; sd+=wd[k]; }
    sums[0]=st; sums[1]=sd;
  }
  __syncthreads();
  float* row = trans + (size_t)i*NS;
  for (int c=tid;c<NS;c+=256) row[c]=0.f;
  __syncthreads();
  if (tid<16){
    if (tid<15){
      int j = (int)(wink[tid] & 0xffffffffull);
      row[j] = wt[tid]/sums[0];
      kidx[i*16+tid] = j;
      kwd[i*16+tid]  = wd[tid]/sums[1];
    } else {
      kidx[i*16+15] = 0;
      kwd[i*16+15]  = 0.f;        // slot 15 contributes w*d = 0, added last
    }
  }
}

// ---------------- 100-iteration sparse power iteration ----------------
// Vectorized: 8 x 16B loads per row (padded stride-16 layout) instead of 30
// scalar loads. Sum order k=0..14 preserved; slot 15 adds 0.f last ->
// bitwise-identical d trajectory.
__global__ void __launch_bounds__(1024) k_power(const int* __restrict__ kidx,
                                                const float* __restrict__ kwd,
                                                float* __restrict__ outPT){
  __shared__ float d[4096];
  __shared__ float dn[4096];
  __shared__ float red[16];
  int tid = threadIdx.x;
  int lane = tid & 63, wv = tid >> 6;
  for (int t=tid;t<4096;t+=1024) d[t] = (t==0)?1.f:0.f;
  __syncthreads();
  for (int it=0; it<100; it++){
    float lmax = 0.f;
    #pragma unroll
    for (int s=0;s<4;s++){
      int r = tid + s*1024;
      const float4* wp = (const float4*)(kwd + (size_t)r*16);
      const int4*   ip = (const int4*)  (kidx + (size_t)r*16);
      float4 w0=wp[0], w1=wp[1], w2=wp[2], w3=wp[3];
      int4   i0=ip[0], i1=ip[1], i2=ip[2], i3=ip[3];
      float a = 0.f;
      a += w0.x*d[i0.x]; a += w0.y*d[i0.y]; a += w0.z*d[i0.z]; a += w0.w*d[i0.w];
      a += w1.x*d[i1.x]; a += w1.y*d[i1.y]; a += w1.z*d[i1.z]; a += w1.w*d[i1.w];
      a += w2.x*d[i2.x]; a += w2.y*d[i2.y]; a += w2.z*d[i2.z]; a += w2.w*d[i2.w];
      a += w3.x*d[i3.x]; a += w3.y*d[i3.y]; a += w3.z*d[i3.z]; a += w3.w*d[i3.w];
      dn[r]=a;
      lmax = fmaxf(lmax, a);
    }
    #pragma unroll
    for (int off=32; off; off>>=1) lmax = fmaxf(lmax, __shfl_down(lmax, off, 64));
    if (lane==0) red[wv]=lmax;
    __syncthreads();
    float m = red[0];
    #pragma unroll
    for (int w=1;w<16;w++) m = fmaxf(m, red[w]);
    for (int r=tid;r<4096;r+=1024) d[r]=dn[r]/m;
    __syncthreads();
  }
  for (int t=tid;t<4096;t+=1024) outPT[t]=d[t];
}

// ---------------- host ----------------
// Footprint ~17.22 MB (< 22.42 MB proven). Ah (padded 1000x1024 fp64) dies
// after k_post; sqv/kidx/kwd overlay it.
extern "C" void kernel_launch(void* const* d_in, const int* in_sizes, int n_in,
                              void* d_out, int out_size, void* d_ws, size_t ws_size,
                              hipStream_t stream){
  const float* x = (const float*)d_in[0];
  float* out = (float*)d_out;
  char* base = (char*)d_ws;

  double* Ah     = (double*)(base + 0);            // 8,192,000 (dead after k_post)
  float*  sqv    = (float*) (base + 0);            //    16,384 overlay
  int*    kidx   = (int*)   (base + 16384);        //   262,144 overlay (stride-16)
  float*  kwd    = (float*) (base + 278528);       //   262,144 overlay (ends 540,672)
  double* Vh     = (double*)(base + 8192000);      // 8,000,000
  double* V50    = (double*)(base + 16192000);     //   400,000
  float*  E50    = (float*) (base + 16592000);     //   200,000
  float*  part   = (float*) (base + 16792000);     //   256,000
  float*  mean   = (float*) (base + 17048000);     //     4,000
  double* tauv   = (double*)(base + 17052000);     //     8,000
  double* betaH  = (double*)(base + 17060000);     //     8,000
  double* alphaH = (double*)(base + 17068000);     //     8,000
  double* w1a    = (double*)(base + 17076000);     //     8,000
  double* w1b    = (double*)(base + 17084000);     //     8,000
  double* cola   = (double*)(base + 17092000);     //     8,000
  double* colb   = (double*)(base + 17100000);     //     8,000
  double* lamT   = (double*)(base + 17108000);     //       400
  float*  sgnv   = (float*) (base + 17108400);     //       200
  unsigned* gen  = (unsigned*)(base + 17200000);   //         4 (64B-aligned)
  unsigned* flags= (unsigned*)(base + 17200064);   //    16,000 (250 x 64B lines)

  k_colsum<<<64,256,0,stream>>>(x, part);
  k_colmean<<<4,256,0,stream>>>(part, mean);
  k_barinit<<<1,256,0,stream>>>(flags, gen);
  k_cov<<<dim3(16,16),dim3(16,16),0,stream>>>(x, mean, Ah);

  // persistent fp64 Householder tridiagonalization (single launch, 998 steps)
  k_hh_all<<<HH_GRID,256,0,stream>>>(Ah, Vh, tauv, betaH, w1a, w1b, cola, colb,
                                     flags, gen);

  // fin + extract + top-50 Sturm bisection
  k_post<<<1,64,0,stream>>>(Ah, Vh, tauv, w1b, alphaH, betaH, lamT);

  // inverse iteration + D&C sign replication (fused)
  k_invsign<<<50,256,0,stream>>>(alphaH, betaH, lamT, V50, sgnv);

  // back-transform + sign -> eigenvectors, then outputs
  k_applyQm<<<50,256,0,stream>>>(Vh, tauv, V50, sgnv, E50);
  k_pca<<<64,256,0,stream>>>(x, mean, E50, out + PCA_OFF);
  k_rowsq<<<16,256,0,stream>>>(out + PCA_OFF, sqv);
  k_knn<<<4096,256,0,stream>>>(out + PCA_OFF, sqv, out + TR_OFF, kidx, kwd);
  k_power<<<1,1024,0,stream>>>(kidx, kwd, out);
}